// Round 2
// baseline (4627.799 us; speedup 1.0000x reference)
//
#include <hip/hip_runtime.h>
#include <math.h>

#define NP 11
#define NPB 4   // nodes per block (1 wave per node, 256 threads)

__device__ __constant__ int g_l1[NP]   = {0,1,2,0,1,1,2,0,1,2,2};
__device__ __constant__ int g_l2[NP]   = {0,1,2,1,0,2,1,2,1,0,2};
__device__ __constant__ int g_l3[NP]   = {0,0,0,1,1,1,1,2,2,2,2};
__device__ __constant__ int g_coff[NP] = {0,1,10,35,44,53,98,143,168,213,238}; // offsets into 363-float w3j table

// ---------------- Wigner-3j precompute (exact replica of reference, fp64) ----------------
__device__ double dfact(int n){ double r=1.0; for(int i=2;i<=n;++i) r*=(double)i; return r; }

__device__ double su2_cg(int j1,int m1,int j2,int m2,int j3,int m3){
  if(m1+m2!=m3) return 0.0;
  int vmin=-j1+j2+m3; if(-j1+m1>vmin) vmin=-j1+m1; if(vmin<0) vmin=0;
  int vmax=j2+j3+m1; int t=j3-j1+j2; if(t<vmax) vmax=t; t=j3+m3; if(t<vmax) vmax=t;
  double C = sqrt((double)(2*j3+1)*dfact(j3+j1-j2)*dfact(j3-j1+j2)*dfact(j1+j2-j3)
      *dfact(j3+m3)*dfact(j3-m3)
      /(dfact(j1+j2+j3+1)*dfact(j1-m1)*dfact(j1+m1)*dfact(j2-m2)*dfact(j2+m2)));
  double S=0.0;
  for(int v=vmin;v<=vmax;++v){
    double sg = ((v+j2+m2)&1)? -1.0:1.0;
    S += sg*dfact(j2+j3+m1-v)*dfact(j1-m1+v)
        /(dfact(v)*dfact(j3-j1+j2-v)*dfact(j3+m3-v)*dfact(v+j1-j2-m3));
  }
  return C*S;
}

// element (r,c) of e3nn's complex->real change-of-basis qmat(l), incl (-i)^l factor
__device__ void qelem(int l,int r,int c,double &re,double &im){
  int m=r-l; double a=0.0,b=0.0; const double s=0.70710678118654752440;
  if(m<0){ if(c==l-m) a=s; else if(c==l+m) b=-s; }
  else if(m==0){ if(c==l) a=1.0; }
  else { double sg=(m&1)?-1.0:1.0; if(c==l+m) a=sg*s; else if(c==l-m) b=sg*s; }
  if(l==1){ double tt=a; a=b; b=-tt; }       // *(-i)
  else if(l==2){ a=-a; b=-b; }               // *(-1)
  re=a; im=b;
}

__global__ void w3j_init(float* __restrict__ ws){
  int p=blockIdx.x;
  int l1=g_l1[p], l2=g_l2[p], l3=g_l3[p];
  int d1=2*l1+1, d2=2*l2+1, d3=2*l3+1;
  int tot=d1*d2*d3;
  __shared__ double cg[125];
  __shared__ double outv[125];
  __shared__ double nrm;
  for(int t=threadIdx.x;t<tot;t+=blockDim.x){
    int i=t/(d2*d3), k=(t/d3)%d2, n=t%d3;
    cg[t]=su2_cg(l1,i-l1,l2,k-l2,l3,n-l3);
  }
  __syncthreads();
  for(int t=threadIdx.x;t<tot;t+=blockDim.x){
    int a=t/(d2*d3), b=(t/d3)%d2, c=t%d3;
    double sre=0.0;
    for(int i=0;i<d1;++i){ double q1r,q1i; qelem(l1,i,a,q1r,q1i);
      for(int k=0;k<d2;++k){ double q2r,q2i; qelem(l2,k,b,q2r,q2i);
        double pr=q1r*q2r-q1i*q2i, pi=q1r*q2i+q1i*q2r;
        for(int n=0;n<d3;++n){ double q3r,q3i; qelem(l3,n,c,q3r,q3i);
          sre += (pr*q3r + pi*q3i) * cg[(i*d2+k)*d3+n];   // Re[(pr+i pi)*conj(q3)]
        }
      }
    }
    outv[t]=sre;
  }
  __syncthreads();
  if(threadIdx.x==0){
    double s=0.0; for(int t=0;t<tot;++t) s+=outv[t]*outv[t];
    nrm=sqrt(s);
  }
  __syncthreads();
  for(int t=threadIdx.x;t<tot;t+=blockDim.x)
    ws[g_coff[p]+t]=(float)(outv[t]/nrm);
}

// ---------------- dtype probe: is this buffer bf16 or fp32? ----------------
// bf16 N(0,1) shorts have exponent field in ~[0x70,0x8E]; fp32 low-halves are
// random bits -> ~40% wild. Writes 1.0 (fp32) / 0.0 (bf16) to *flag.
__global__ void dtype_probe(const unsigned short* __restrict__ p, int nelem,
                            float* __restrict__ flag){
  __shared__ int cnt;
  if(threadIdx.x==0) cnt=0;
  __syncthreads();
  int M = nelem < 4096 ? nelem : 4096;
  int c=0;
  for(int t=threadIdx.x;t<M;t+=blockDim.x){
    unsigned e=((unsigned)p[t]>>7)&0xFFu;
    if(e!=0u && (e<0x70u || e>0x8Eu)) ++c;
  }
  atomicAdd(&cnt,c);
  __syncthreads();
  if(threadIdx.x==0) *flag = (cnt*8 > M) ? 1.0f : 0.0f;
}

// ---------------- main fused kernel ----------------
__device__ __forceinline__ float bfu(unsigned int v){ return __uint_as_float(v<<16); }
__device__ __forceinline__ unsigned int rne16(float f){
  unsigned int ui=__float_as_uint(f);
  return (ui+0x7fffu+((ui>>16)&1u))>>16;
}

// stage 1: b[u,v,k] = scale * sum_{i,j} C[i,j,k] x[u,i] x[v,j]
template<int D1,int D2,int D3>
__device__ __forceinline__ void stage1(const float* __restrict__ sx,
                                       const float* __restrict__ cg, float scale,
                                       float* __restrict__ sb, int lane){
  constexpr int O1=(D1==1)?0:((D1==3)?16:64);
  constexpr int O2=(D2==1)?0:((D2==3)?16:64);
  #pragma unroll
  for(int t=0;t<4;++t){
    int q=lane+(t<<6);
    int u=q>>4, v=q&15;
    float x1[D1],x2[D2],acc[D3];
    #pragma unroll
    for(int i=0;i<D1;++i) x1[i]=sx[O1+u*D1+i]*scale;
    #pragma unroll
    for(int j=0;j<D2;++j) x2[j]=sx[O2+v*D2+j];
    #pragma unroll
    for(int k=0;k<D3;++k) acc[k]=0.f;
    #pragma unroll
    for(int i=0;i<D1;++i)
      #pragma unroll
      for(int j=0;j<D2;++j){
        float pp=x1[i]*x2[j];
        #pragma unroll
        for(int k=0;k<D3;++k) acc[k]+=cg[(i*D2+j)*D3+k]*pp;
      }
    #pragma unroll
    for(int k=0;k<D3;++k) sb[q*5+k]=acc[k];
  }
}

// stage 2: o[tp,w,k] += sum_{uv} b[uv,k] * W_tp[uv,w]
template<int D3>
__device__ __forceinline__ void stage2(const unsigned short* __restrict__ sWb,
                                       const float* __restrict__ sb,
                                       float* __restrict__ so, int lane){
  constexpr int OO=(D3==1)?0:((D3==3)?16:64);
  const int slice=lane>>4, w=lane&15;
  float acc[3][D3];
  #pragma unroll
  for(int tp=0;tp<3;++tp)
    #pragma unroll
    for(int k=0;k<D3;++k) acc[tp][k]=0.f;
  const float* bp = sb + slice*5;               // uv = it*4 + slice -> sb[uv*5+k]
  const unsigned short* wp = sWb + lane;        // W lds idx = it*64 + lane
  for(int ch=0;ch<8;++ch){
    float br[8*D3];
    #pragma unroll
    for(int it2=0;it2<8;++it2)
      #pragma unroll
      for(int k=0;k<D3;++k) br[it2*D3+k]=bp[(ch*8+it2)*20+k];
    #pragma unroll
    for(int tp=0;tp<3;++tp)
      #pragma unroll
      for(int it2=0;it2<8;++it2){
        float wvv=bfu((unsigned int)wp[tp*4096+((ch*8+it2)<<6)]);
        #pragma unroll
        for(int k=0;k<D3;++k) acc[tp][k]+=wvv*br[it2*D3+k];
      }
  }
  #pragma unroll
  for(int tp=0;tp<3;++tp)
    #pragma unroll
    for(int k=0;k<D3;++k){
      float a=acc[tp][k];
      a+=__shfl_xor(a,16,64);
      a+=__shfl_xor(a,32,64);
      if(slice==0) so[tp*144+OO+w*D3+k]+=a;
    }
}

__global__ __launch_bounds__(256) void tfn_main(
    const unsigned short* __restrict__ xin,
    const unsigned short* __restrict__ wq,
    const unsigned short* __restrict__ wk,
    const unsigned short* __restrict__ wv,
    const unsigned short* __restrict__ wd,
    const float* __restrict__ c3j,
    unsigned short* __restrict__ outp, int N)
{
  __shared__ unsigned short sWb[3*4096];  // current path's w_q|w_k|w_v as bf16 (24 KB)
  __shared__ float sB[NPB][1280];         // b[uv][k], stride 5 (20 KB)
  __shared__ float sX[NPB][144];
  __shared__ float sO[NPB][432];          // q|k|v outputs per node
  __shared__ float sWd[768];
  __shared__ float sCdot[36];

  const int tid=threadIdx.x;
  const int wave=tid>>6, lane=tid&63;
  const int node0=blockIdx.x*NPB;
  const int node=node0+wave;

  // dtype flags (written by dtype_probe): c3j[363..367] = {x, wq, wk, wv, wd}
  const int xf32 = c3j[363]!=0.0f;
  const int qf32 = c3j[364]!=0.0f;
  const int kf32 = c3j[365]!=0.0f;
  const int vf32 = c3j[366]!=0.0f;
  const int df32 = c3j[367]!=0.0f;

  // one-time staging of x
  if(!xf32){
    for(int t=tid;t<NPB*36;t+=256){
      int nn=t/36, w4=t%36;
      if(node0+nn<N){
        uint2 u=((const uint2*)(xin+(size_t)(node0+nn)*144))[w4];
        float* dst=&sX[nn][w4*4];
        dst[0]=bfu(u.x&0xffffu); dst[1]=bfu(u.x>>16);
        dst[2]=bfu(u.y&0xffffu); dst[3]=bfu(u.y>>16);
      }
    }
  }else{
    const float* xf=(const float*)xin;
    for(int t=tid;t<NPB*144;t+=256){
      int nn=t/144, f=t%144;
      if(node0+nn<N) sX[nn][f]=xf[(size_t)(node0+nn)*144+f];
    }
  }
  if(!df32){ for(int t=tid;t<768;t+=256) sWd[t]=bfu((unsigned int)wd[t]); }
  else     { const float* wdf=(const float*)wd; for(int t=tid;t<768;t+=256) sWd[t]=wdf[t]; }
  for(int t=tid;t<35;t+=256) sCdot[t]=c3j[t];
  for(int t=tid;t<NPB*432;t+=256) (&sO[0][0])[t]=0.f;
  __syncthreads();

  const float scl[3]={0.03608439182435161f,0.05412658773652741f,0.06987712429686843f};

  for(int p=0;p<NP;++p){
    const int l3=g_l3[p];
    // stage weights for this path (bf16 in LDS either way)
    for(int t=tid;t<3072;t+=256){
      int tp=t>>10, g=t&1023;
      const unsigned short* ww=(tp==0)?wq:((tp==1)?wk:wv);
      const int f32=(tp==0)?qf32:((tp==1)?kf32:vf32);
      if(!f32){
        ((uint2*)sWb)[t]=((const uint2*)(ww+(size_t)p*4096))[g];
      }else{
        const float4 v=((const float4*)((const float*)ww+(size_t)p*4096))[g];
        uint2 u;
        u.x=rne16(v.x)|(rne16(v.y)<<16);
        u.y=rne16(v.z)|(rne16(v.w)<<16);
        ((uint2*)sWb)[t]=u;
      }
    }
    // stage 1 (different buffers than weight staging)
    if(node<N){
      const float* cg=c3j+g_coff[p];
      const float sc_=scl[l3];
      switch(p){
        case 0: stage1<1,1,1>(sX[wave],cg,sc_,sB[wave],lane); break;
        case 1: stage1<3,3,1>(sX[wave],cg,sc_,sB[wave],lane); break;
        case 2: stage1<5,5,1>(sX[wave],cg,sc_,sB[wave],lane); break;
        case 3: stage1<1,3,3>(sX[wave],cg,sc_,sB[wave],lane); break;
        case 4: stage1<3,1,3>(sX[wave],cg,sc_,sB[wave],lane); break;
        case 5: stage1<3,5,3>(sX[wave],cg,sc_,sB[wave],lane); break;
        case 6: stage1<5,3,3>(sX[wave],cg,sc_,sB[wave],lane); break;
        case 7: stage1<1,5,5>(sX[wave],cg,sc_,sB[wave],lane); break;
        case 8: stage1<3,3,5>(sX[wave],cg,sc_,sB[wave],lane); break;
        case 9: stage1<5,1,5>(sX[wave],cg,sc_,sB[wave],lane); break;
        default: stage1<5,5,5>(sX[wave],cg,sc_,sB[wave],lane); break;
      }
    }
    __syncthreads();
    if(node<N){
      if(l3==0)      stage2<1>(sWb,sB[wave],sO[wave],lane);
      else if(l3==1) stage2<3>(sWb,sB[wave],sO[wave],lane);
      else           stage2<5>(sWb,sB[wave],sO[wave],lane);
    }
    __syncthreads();
  }

  if(node<N){
    const float* qv=sO[wave];
    const float* kv=sO[wave]+144;
    float part=0.f;
    #pragma unroll
    for(int t=0;t<4;++t){
      int pq=lane+(t<<6);
      int u=pq>>4, v=pq&15;
      float s3=sWd[u*16+v]*(sCdot[0]*qv[u]*kv[v]);
      float t1=0.f;
      #pragma unroll
      for(int i=0;i<3;++i)
        #pragma unroll
        for(int j=0;j<3;++j)
          t1+=qv[16+u*3+i]*sCdot[1+i*3+j]*kv[16+v*3+j];
      s3+=sWd[256+u*16+v]*t1;
      float t2=0.f;
      #pragma unroll
      for(int i=0;i<5;++i)
        #pragma unroll
        for(int j=0;j<5;++j)
          t2+=qv[64+u*5+i]*sCdot[10+i*5+j]*kv[64+v*5+j];
      s3+=sWd[512+u*16+v]*t2;
      part+=s3;
    }
    #pragma unroll
    for(int off=1;off<64;off<<=1) part+=__shfl_xor(part,off,64);
    float dd=part*0.03608439182435161f;          // * sqrt(1/768)
    float ex=dd*(1.0f/12.0f);                    // / sqrt(144)
    ex=fminf(fmaxf(ex,-80.f),80.f);              // NaN guard (|ex|<<80 for sane data)
    float e=expf(ex);
    float attn=e/(e+1e-10f);
    const float* vv=sO[wave]+288;
    if(!xf32){
      unsigned short* ob=outp+(size_t)node*144;
      for(int f=lane;f<144;f+=64){
        float val=attn*vv[f];
        float r=(val>0.f)?val:expm1f(val);
        ob[f]=(unsigned short)rne16(r);
      }
    }else{
      float* ob=(float*)outp+(size_t)node*144;
      for(int f=lane;f<144;f+=64){
        float val=attn*vv[f];
        ob[f]=(val>0.f)?val:expm1f(val);
      }
    }
  }
}

extern "C" void kernel_launch(void* const* d_in, const int* in_sizes, int n_in,
                              void* d_out, int out_size, void* d_ws, size_t ws_size,
                              hipStream_t stream){
  (void)n_in; (void)out_size; (void)ws_size;
  const unsigned short* x =(const unsigned short*)d_in[0];
  const unsigned short* wq=(const unsigned short*)d_in[4];
  const unsigned short* wk=(const unsigned short*)d_in[5];
  const unsigned short* wv=(const unsigned short*)d_in[6];
  const unsigned short* wd=(const unsigned short*)d_in[7];
  float* c3j=(float*)d_ws;                      // [0..362] w3j tables, [363..367] dtype flags
  int N=in_sizes[0]/144;
  w3j_init<<<dim3(NP),dim3(128),0,stream>>>(c3j);
  dtype_probe<<<dim3(1),dim3(256),0,stream>>>(x ,in_sizes[0],c3j+363);
  dtype_probe<<<dim3(1),dim3(256),0,stream>>>(wq,in_sizes[4],c3j+364);
  dtype_probe<<<dim3(1),dim3(256),0,stream>>>(wk,in_sizes[5],c3j+365);
  dtype_probe<<<dim3(1),dim3(256),0,stream>>>(wv,in_sizes[6],c3j+366);
  dtype_probe<<<dim3(1),dim3(256),0,stream>>>(wd,in_sizes[7],c3j+367);
  int nb=(N+NPB-1)/NPB;
  tfn_main<<<dim3(nb),dim3(256),0,stream>>>(x,wq,wk,wv,wd,c3j,(unsigned short*)d_out,N);
}

// Round 3
// 783.154 us; speedup vs baseline: 5.9092x; 5.9092x over previous
//
#include <hip/hip_runtime.h>
#include <math.h>

#define NP 11
#define NN 8    // nodes per block

__device__ __constant__ int g_l1[NP]   = {0,1,2,0,1,1,2,0,1,2,2};
__device__ __constant__ int g_l2[NP]   = {0,1,2,1,0,2,1,2,1,0,2};
__device__ __constant__ int g_l3[NP]   = {0,0,0,1,1,1,1,2,2,2,2};
__device__ __constant__ int g_coff[NP] = {0,1,10,35,44,53,98,143,168,213,238};

typedef _Float16 half8 __attribute__((ext_vector_type(8)));
typedef float f32x4 __attribute__((ext_vector_type(4)));

// ---------------- Wigner-3j precompute (exact replica of reference, fp64) ----------------
__device__ double dfact(int n){ double r=1.0; for(int i=2;i<=n;++i) r*=(double)i; return r; }

__device__ double su2_cg(int j1,int m1,int j2,int m2,int j3,int m3){
  if(m1+m2!=m3) return 0.0;
  int vmin=-j1+j2+m3; if(-j1+m1>vmin) vmin=-j1+m1; if(vmin<0) vmin=0;
  int vmax=j2+j3+m1; int t=j3-j1+j2; if(t<vmax) vmax=t; t=j3+m3; if(t<vmax) vmax=t;
  double C = sqrt((double)(2*j3+1)*dfact(j3+j1-j2)*dfact(j3-j1+j2)*dfact(j1+j2-j3)
      *dfact(j3+m3)*dfact(j3-m3)
      /(dfact(j1+j2+j3+1)*dfact(j1-m1)*dfact(j1+m1)*dfact(j2-m2)*dfact(j2+m2)));
  double S=0.0;
  for(int v=vmin;v<=vmax;++v){
    double sg = ((v+j2+m2)&1)? -1.0:1.0;
    S += sg*dfact(j2+j3+m1-v)*dfact(j1-m1+v)
        /(dfact(v)*dfact(j3-j1+j2-v)*dfact(j3+m3-v)*dfact(v+j1-j2-m3));
  }
  return C*S;
}

__device__ void qelem(int l,int r,int c,double &re,double &im){
  int m=r-l; double a=0.0,b=0.0; const double s=0.70710678118654752440;
  if(m<0){ if(c==l-m) a=s; else if(c==l+m) b=-s; }
  else if(m==0){ if(c==l) a=1.0; }
  else { double sg=(m&1)?-1.0:1.0; if(c==l+m) a=sg*s; else if(c==l-m) b=sg*s; }
  if(l==1){ double tt=a; a=b; b=-tt; }
  else if(l==2){ a=-a; b=-b; }
  re=a; im=b;
}

__global__ void w3j_init(float* __restrict__ ws){
  int p=blockIdx.x;
  int l1=g_l1[p], l2=g_l2[p], l3=g_l3[p];
  int d1=2*l1+1, d2=2*l2+1, d3=2*l3+1;
  int tot=d1*d2*d3;
  __shared__ double cg[125];
  __shared__ double outv[125];
  __shared__ double nrm;
  for(int t=threadIdx.x;t<tot;t+=blockDim.x){
    int i=t/(d2*d3), k=(t/d3)%d2, n=t%d3;
    cg[t]=su2_cg(l1,i-l1,l2,k-l2,l3,n-l3);
  }
  __syncthreads();
  for(int t=threadIdx.x;t<tot;t+=blockDim.x){
    int a=t/(d2*d3), b=(t/d3)%d2, c=t%d3;
    double sre=0.0;
    for(int i=0;i<d1;++i){ double q1r,q1i; qelem(l1,i,a,q1r,q1i);
      for(int k=0;k<d2;++k){ double q2r,q2i; qelem(l2,k,b,q2r,q2i);
        double pr=q1r*q2r-q1i*q2i, pi=q1r*q2i+q1i*q2r;
        for(int n=0;n<d3;++n){ double q3r,q3i; qelem(l3,n,c,q3r,q3i);
          sre += (pr*q3r + pi*q3i) * cg[(i*d2+k)*d3+n];
        }
      }
    }
    outv[t]=sre;
  }
  __syncthreads();
  if(threadIdx.x==0){
    double s=0.0; for(int t=0;t<tot;++t) s+=outv[t]*outv[t];
    nrm=sqrt(s);
  }
  __syncthreads();
  for(int t=threadIdx.x;t<tot;t+=blockDim.x)
    ws[g_coff[p]+t]=(float)(outv[t]/nrm);
}

// ---------------- dtype probe ----------------
__global__ void dtype_probe(const unsigned short* __restrict__ p, int nelem,
                            float* __restrict__ flag){
  __shared__ int cnt;
  if(threadIdx.x==0) cnt=0;
  __syncthreads();
  int M = nelem < 4096 ? nelem : 4096;
  int c=0;
  for(int t=threadIdx.x;t<M;t+=blockDim.x){
    unsigned e=((unsigned)p[t]>>7)&0xFFu;
    if(e!=0u && (e<0x70u || e>0x8Eu)) ++c;
  }
  atomicAdd(&cnt,c);
  __syncthreads();
  if(threadIdx.x==0) *flag = (cnt*8 > M) ? 1.0f : 0.0f;
}

// ---------------- helpers ----------------
__device__ __forceinline__ float bfu(unsigned int v){ return __uint_as_float(v<<16); }
__device__ __forceinline__ unsigned int rne16(float f){
  unsigned int ui=__float_as_uint(f);
  return (ui+0x7fffu+((ui>>16)&1u))>>16;
}
__device__ __forceinline__ unsigned short h16(float f){
  _Float16 h=(_Float16)f;
  return __builtin_bit_cast(unsigned short,h);
}

// stage 1: A[r=k*8+node][uv] (fp16, packed pairs) = scale * sum_{i,j} C[i,j,k] x[u,i] x[v,j]
template<int D1,int D2,int D3>
__device__ __forceinline__ void stage1(const float* __restrict__ sX,
                                       const float* __restrict__ cg, float scale,
                                       unsigned int* __restrict__ sAu,
                                       int tid, int nvalid){
  constexpr int O1=(D1==1)?0:((D1==3)?16:64);
  constexpr int O2=(D2==1)?0:((D2==3)?16:64);
  #pragma unroll
  for(int i4=0;i4<4;++i4){
    int it=tid+(i4<<8);
    int node=it>>7, uvp=it&127;
    if(node<nvalid){
      int uv=uvp<<1, u=uv>>4, v=uv&15;
      const float* xs=sX+node*148;
      float x1[D1],x2a[D2],x2b[D2],aa[D3],ab[D3];
      #pragma unroll
      for(int i=0;i<D1;++i) x1[i]=xs[O1+u*D1+i]*scale;
      #pragma unroll
      for(int j=0;j<D2;++j){ x2a[j]=xs[O2+v*D2+j]; x2b[j]=xs[O2+(v+1)*D2+j]; }
      #pragma unroll
      for(int k=0;k<D3;++k){ aa[k]=0.f; ab[k]=0.f; }
      #pragma unroll
      for(int i=0;i<D1;++i)
        #pragma unroll
        for(int j=0;j<D2;++j){
          float pa=x1[i]*x2a[j], pb=x1[i]*x2b[j];
          #pragma unroll
          for(int k=0;k<D3;++k){
            float c=cg[(i*D2+j)*D3+k];
            aa[k]+=c*pa; ab[k]+=c*pb;
          }
        }
      #pragma unroll
      for(int k=0;k<D3;++k){
        unsigned int pk=(unsigned int)h16(aa[k]) | ((unsigned int)h16(ab[k])<<16);
        sAu[(k*8+node)*132+uvp]=pk;
      }
    }
  }
}

// stage 2: MFMA over tiles; C rows r=Mtile*16+quad*4+reg -> (k=r>>3, node=r&7)
template<int L3>
__device__ __forceinline__ void stage2(const unsigned int* __restrict__ sAu,
                                       const unsigned int* __restrict__ sWu,
                                       float* __restrict__ sO,
                                       int wave, int lane){
  constexpr int D3=2*L3+1;
  constexpr int Mtiles=L3+1;
  constexpr int OO=(L3==0)?0:((L3==1)?16:64);
  constexpr int P=Mtiles*3;
  const int n16=lane&15, quad=lane>>4;
  for(int pid=wave;pid<P;pid+=4){
    int tp=pid%3, Mtile=pid/3;
    const unsigned int* ap=sAu+(Mtile*16+n16)*132+quad*4;
    const unsigned int* bp=sWu+tp*2112+n16*132+quad*4;
    f32x4 acc={0.f,0.f,0.f,0.f};
    #pragma unroll
    for(int ks=0;ks<8;++ks){
      half8 af=*reinterpret_cast<const half8*>(ap+ks*16);
      half8 bf=*reinterpret_cast<const half8*>(bp+ks*16);
      acc=__builtin_amdgcn_mfma_f32_16x16x32_f16(af,bf,acc,0,0,0);
    }
    #pragma unroll
    for(int reg=0;reg<4;++reg){
      int row=Mtile*16+quad*4+reg;
      int k=row>>3, node=row&7;
      if(k<D3) sO[node*440+tp*144+OO+n16*D3+k]+=acc[reg];
    }
  }
}

__global__ __launch_bounds__(256,2) void tfn_main(
    const unsigned short* __restrict__ xin,
    const unsigned short* __restrict__ wq,
    const unsigned short* __restrict__ wk,
    const unsigned short* __restrict__ wv,
    const unsigned short* __restrict__ wd,
    const float* __restrict__ c3j,
    unsigned short* __restrict__ outp, int N)
{
  __shared__ __align__(16) unsigned int sAu[48*132];   // fp16 A, rows padded to 264 halves
  __shared__ __align__(16) unsigned int sWu[3*16*132]; // fp16 W^T per tp: [w][uv]
  __shared__ float sO[NN*440];
  __shared__ float sX[NN*148];
  __shared__ float sWd[768];
  __shared__ float sCdot[36];

  const int tid=threadIdx.x;
  const int wave=tid>>6, lane=tid&63;
  const int node0=blockIdx.x*NN;
  const int nvalid=(N-node0)<NN?(N-node0):NN;

  const int xf32 = c3j[363]!=0.0f;
  const int qf32 = c3j[364]!=0.0f;
  const int kf32 = c3j[365]!=0.0f;
  const int vf32 = c3j[366]!=0.0f;
  const int df32 = c3j[367]!=0.0f;

  // stage x
  if(!xf32){
    for(int t=tid;t<NN*36;t+=256){
      int nn=t/36, w4=t%36;
      if(nn<nvalid){
        uint2 u=((const uint2*)(xin+(size_t)(node0+nn)*144))[w4];
        float* dst=&sX[nn*148+w4*4];
        dst[0]=bfu(u.x&0xffffu); dst[1]=bfu(u.x>>16);
        dst[2]=bfu(u.y&0xffffu); dst[3]=bfu(u.y>>16);
      }
    }
  }else{
    const float* xf=(const float*)xin;
    for(int t=tid;t<NN*144;t+=256){
      int nn=t/144, f=t%144;
      if(nn<nvalid) sX[nn*148+f]=xf[(size_t)(node0+nn)*144+f];
    }
  }
  if(!df32){ for(int t=tid;t<768;t+=256) sWd[t]=bfu((unsigned int)wd[t]); }
  else     { const float* wdf=(const float*)wd; for(int t=tid;t<768;t+=256) sWd[t]=wdf[t]; }
  for(int t=tid;t<35;t+=256) sCdot[t]=c3j[t];
  for(int t=tid;t<NN*440;t+=256) sO[t]=0.f;
  __syncthreads();

  const float scl[3]={0.03608439182435161f,0.05412658773652741f,0.06987712429686843f};

  for(int p=0;p<NP;++p){
    const int l3=g_l3[p];
    // ---- stage weights: transpose to [tp][w][uv], fp16, packed uv pairs ----
    for(int t=tid;t<1536;t+=256){
      int tp=t>>9, g=t&511, uvp=g>>2, wg=g&3, uv=uvp<<1;
      float f0[4],f1[4];
      const int f32=(tp==0)?qf32:((tp==1)?kf32:vf32);
      const unsigned short* ww=(tp==0)?wq:((tp==1)?wk:wv);
      if(!f32){
        const unsigned short* wwp=ww+(size_t)p*4096;
        uint2 e0=*(const uint2*)(wwp+uv*16+wg*4);
        uint2 e1=*(const uint2*)(wwp+(uv+1)*16+wg*4);
        f0[0]=bfu(e0.x&0xffffu); f0[1]=bfu(e0.x>>16); f0[2]=bfu(e0.y&0xffffu); f0[3]=bfu(e0.y>>16);
        f1[0]=bfu(e1.x&0xffffu); f1[1]=bfu(e1.x>>16); f1[2]=bfu(e1.y&0xffffu); f1[3]=bfu(e1.y>>16);
      }else{
        const float* wwf=(const float*)ww+(size_t)p*4096;
        float4 a0=((const float4*)wwf)[uv*4+wg];
        float4 a1=((const float4*)wwf)[(uv+1)*4+wg];
        f0[0]=a0.x;f0[1]=a0.y;f0[2]=a0.z;f0[3]=a0.w;
        f1[0]=a1.x;f1[1]=a1.y;f1[2]=a1.z;f1[3]=a1.w;
      }
      #pragma unroll
      for(int i=0;i<4;++i){
        unsigned int pk=(unsigned int)h16(f0[i]) | ((unsigned int)h16(f1[i])<<16);
        sWu[tp*2112+(wg*4+i)*132+uvp]=pk;
      }
    }
    // ---- stage 1 ----
    {
      const float* cg=c3j+g_coff[p];
      const float sc_=scl[l3];
      switch(p){
        case 0: stage1<1,1,1>(sX,cg,sc_,sAu,tid,nvalid); break;
        case 1: stage1<3,3,1>(sX,cg,sc_,sAu,tid,nvalid); break;
        case 2: stage1<5,5,1>(sX,cg,sc_,sAu,tid,nvalid); break;
        case 3: stage1<1,3,3>(sX,cg,sc_,sAu,tid,nvalid); break;
        case 4: stage1<3,1,3>(sX,cg,sc_,sAu,tid,nvalid); break;
        case 5: stage1<3,5,3>(sX,cg,sc_,sAu,tid,nvalid); break;
        case 6: stage1<5,3,3>(sX,cg,sc_,sAu,tid,nvalid); break;
        case 7: stage1<1,5,5>(sX,cg,sc_,sAu,tid,nvalid); break;
        case 8: stage1<3,3,5>(sX,cg,sc_,sAu,tid,nvalid); break;
        case 9: stage1<5,1,5>(sX,cg,sc_,sAu,tid,nvalid); break;
        default: stage1<5,5,5>(sX,cg,sc_,sAu,tid,nvalid); break;
      }
    }
    __syncthreads();
    // ---- stage 2 (MFMA) ----
    if(l3==0)      stage2<0>(sAu,sWu,sO,wave,lane);
    else if(l3==1) stage2<1>(sAu,sWu,sO,wave,lane);
    else           stage2<2>(sAu,sWu,sO,wave,lane);
    __syncthreads();
  }

  // ---- epilogue: dot, attention, elu, store ----
  for(int nn=0;nn<2;++nn){
    int node=wave*2+nn;
    if(node<nvalid){
      const float* qv=sO+node*440;
      const float* kv=qv+144;
      float part=0.f;
      #pragma unroll
      for(int t=0;t<4;++t){
        int pq=lane+(t<<6);
        int u=pq>>4, v=pq&15;
        float s3=sWd[u*16+v]*(sCdot[0]*qv[u]*kv[v]);
        float t1=0.f;
        #pragma unroll
        for(int i=0;i<3;++i)
          #pragma unroll
          for(int j=0;j<3;++j)
            t1+=qv[16+u*3+i]*sCdot[1+i*3+j]*kv[16+v*3+j];
        s3+=sWd[256+u*16+v]*t1;
        float t2=0.f;
        #pragma unroll
        for(int i=0;i<5;++i)
          #pragma unroll
          for(int j=0;j<5;++j)
            t2+=qv[64+u*5+i]*sCdot[10+i*5+j]*kv[64+v*5+j];
        s3+=sWd[512+u*16+v]*t2;
        part+=s3;
      }
      #pragma unroll
      for(int off=1;off<64;off<<=1) part+=__shfl_xor(part,off,64);
      float dd=part*0.03608439182435161f;
      float ex=dd*(1.0f/12.0f);
      ex=fminf(fmaxf(ex,-80.f),80.f);
      float e=expf(ex);
      float attn=e/(e+1e-10f);
      const float* vv=sO+node*440+288;
      if(!xf32){
        unsigned short* ob=outp+(size_t)(node0+node)*144;
        for(int f=lane;f<144;f+=64){
          float val=attn*vv[f];
          float r=(val>0.f)?val:expm1f(val);
          ob[f]=(unsigned short)rne16(r);
        }
      }else{
        float* ob=(float*)outp+(size_t)(node0+node)*144;
        for(int f=lane;f<144;f+=64){
          float val=attn*vv[f];
          ob[f]=(val>0.f)?val:expm1f(val);
        }
      }
    }
  }
}

extern "C" void kernel_launch(void* const* d_in, const int* in_sizes, int n_in,
                              void* d_out, int out_size, void* d_ws, size_t ws_size,
                              hipStream_t stream){
  (void)n_in; (void)out_size; (void)ws_size;
  const unsigned short* x =(const unsigned short*)d_in[0];
  const unsigned short* wq=(const unsigned short*)d_in[4];
  const unsigned short* wk=(const unsigned short*)d_in[5];
  const unsigned short* wv=(const unsigned short*)d_in[6];
  const unsigned short* wd=(const unsigned short*)d_in[7];
  float* c3j=(float*)d_ws;                      // [0..362] w3j, [363..367] dtype flags
  int N=in_sizes[0]/144;
  w3j_init<<<dim3(NP),dim3(128),0,stream>>>(c3j);
  dtype_probe<<<dim3(1),dim3(256),0,stream>>>(x ,in_sizes[0],c3j+363);
  dtype_probe<<<dim3(1),dim3(256),0,stream>>>(wq,in_sizes[4],c3j+364);
  dtype_probe<<<dim3(1),dim3(256),0,stream>>>(wk,in_sizes[5],c3j+365);
  dtype_probe<<<dim3(1),dim3(256),0,stream>>>(wv,in_sizes[6],c3j+366);
  dtype_probe<<<dim3(1),dim3(256),0,stream>>>(wd,in_sizes[7],c3j+367);
  int nb=(N+NN-1)/NN;
  tfn_main<<<dim3(nb),dim3(256),0,stream>>>(x,wq,wk,wv,wd,c3j,(unsigned short*)d_out,N);
}

// Round 4
// 558.918 us; speedup vs baseline: 8.2799x; 1.4012x over previous
//
#include <hip/hip_runtime.h>
#include <math.h>

#define NP 11
#define NN 8    // nodes per block (512 threads, 8 waves)

__device__ __constant__ int g_l1[NP]   = {0,1,2,0,1,1,2,0,1,2,2};
__device__ __constant__ int g_l2[NP]   = {0,1,2,1,0,2,1,2,1,0,2};
__device__ __constant__ int g_l3[NP]   = {0,0,0,1,1,1,1,2,2,2,2};
__device__ __constant__ int g_coff[NP] = {0,1,10,35,44,53,98,143,168,213,238};

typedef _Float16 half8 __attribute__((ext_vector_type(8)));
typedef _Float16 h2 __attribute__((ext_vector_type(2)));
typedef float f32x4 __attribute__((ext_vector_type(4)));

// ---------------- Wigner-3j precompute (exact replica of reference, fp64) ----------------
__device__ double dfact(int n){ double r=1.0; for(int i=2;i<=n;++i) r*=(double)i; return r; }

__device__ double su2_cg(int j1,int m1,int j2,int m2,int j3,int m3){
  if(m1+m2!=m3) return 0.0;
  int vmin=-j1+j2+m3; if(-j1+m1>vmin) vmin=-j1+m1; if(vmin<0) vmin=0;
  int vmax=j2+j3+m1; int t=j3-j1+j2; if(t<vmax) vmax=t; t=j3+m3; if(t<vmax) vmax=t;
  double C = sqrt((double)(2*j3+1)*dfact(j3+j1-j2)*dfact(j3-j1+j2)*dfact(j1+j2-j3)
      *dfact(j3+m3)*dfact(j3-m3)
      /(dfact(j1+j2+j3+1)*dfact(j1-m1)*dfact(j1+m1)*dfact(j2-m2)*dfact(j2+m2)));
  double S=0.0;
  for(int v=vmin;v<=vmax;++v){
    double sg = ((v+j2+m2)&1)? -1.0:1.0;
    S += sg*dfact(j2+j3+m1-v)*dfact(j1-m1+v)
        /(dfact(v)*dfact(j3-j1+j2-v)*dfact(j3+m3-v)*dfact(v+j1-j2-m3));
  }
  return C*S;
}

__device__ void qelem(int l,int r,int c,double &re,double &im){
  int m=r-l; double a=0.0,b=0.0; const double s=0.70710678118654752440;
  if(m<0){ if(c==l-m) a=s; else if(c==l+m) b=-s; }
  else if(m==0){ if(c==l) a=1.0; }
  else { double sg=(m&1)?-1.0:1.0; if(c==l+m) a=sg*s; else if(c==l-m) b=sg*s; }
  if(l==1){ double tt=a; a=b; b=-tt; }
  else if(l==2){ a=-a; b=-b; }
  re=a; im=b;
}

__global__ void w3j_init(float* __restrict__ ws){
  int p=blockIdx.x;
  int l1=g_l1[p], l2=g_l2[p], l3=g_l3[p];
  int d1=2*l1+1, d2=2*l2+1, d3=2*l3+1;
  int tot=d1*d2*d3;
  __shared__ double cg[125];
  __shared__ double outv[125];
  __shared__ double nrm;
  for(int t=threadIdx.x;t<tot;t+=blockDim.x){
    int i=t/(d2*d3), k=(t/d3)%d2, n=t%d3;
    cg[t]=su2_cg(l1,i-l1,l2,k-l2,l3,n-l3);
  }
  __syncthreads();
  for(int t=threadIdx.x;t<tot;t+=blockDim.x){
    int a=t/(d2*d3), b=(t/d3)%d2, c=t%d3;
    double sre=0.0;
    for(int i=0;i<d1;++i){ double q1r,q1i; qelem(l1,i,a,q1r,q1i);
      for(int k=0;k<d2;++k){ double q2r,q2i; qelem(l2,k,b,q2r,q2i);
        double pr=q1r*q2r-q1i*q2i, pi=q1r*q2i+q1i*q2r;
        for(int n=0;n<d3;++n){ double q3r,q3i; qelem(l3,n,c,q3r,q3i);
          sre += (pr*q3r + pi*q3i) * cg[(i*d2+k)*d3+n];
        }
      }
    }
    outv[t]=sre;
  }
  __syncthreads();
  if(threadIdx.x==0){
    double s=0.0; for(int t=0;t<tot;++t) s+=outv[t]*outv[t];
    nrm=sqrt(s);
  }
  __syncthreads();
  for(int t=threadIdx.x;t<tot;t+=blockDim.x)
    ws[g_coff[p]+t]=(float)(outv[t]/nrm);
}

// ---------------- dtype probe ----------------
__global__ void dtype_probe(const unsigned short* __restrict__ p, int nelem,
                            float* __restrict__ flag){
  __shared__ int cnt;
  if(threadIdx.x==0) cnt=0;
  __syncthreads();
  int M = nelem < 4096 ? nelem : 4096;
  int c=0;
  for(int t=threadIdx.x;t<M;t+=blockDim.x){
    unsigned e=((unsigned)p[t]>>7)&0xFFu;
    if(e!=0u && (e<0x70u || e>0x8Eu)) ++c;
  }
  atomicAdd(&cnt,c);
  __syncthreads();
  if(threadIdx.x==0) *flag = (cnt*8 > M) ? 1.0f : 0.0f;
}

// ---------------- helpers ----------------
__device__ __forceinline__ float bfu(unsigned int v){ return __uint_as_float(v<<16); }
__device__ __forceinline__ unsigned int rne16(float f){
  unsigned int ui=__float_as_uint(f);
  return (ui+0x7fffu+((ui>>16)&1u))>>16;
}
__device__ __forceinline__ unsigned short h16(float f){
  _Float16 h=(_Float16)f;
  return __builtin_bit_cast(unsigned short,h);
}

// phase A: a[lane=(n,vp)][idx=(i*D3+k)] = scale * sum_j C[ijk]*x2[n,2vp+{0,1},j]  (fp16 pair)
template<int D1,int D2,int D3>
__device__ __forceinline__ void phaseA(const float* __restrict__ sX,
                                       const float* __restrict__ cg, float scale,
                                       unsigned int* __restrict__ aPk,
                                       int wave, int lane, int nvalid){
  constexpr int O2=(D2==1)?0:((D2==3)?16:64);
  constexpr int DD=D1*D3;
  constexpr int PER=(DD+7)>>3;
  const int nn=lane>>3, vp=lane&7;
  if(nn>=nvalid) return;
  int i0=wave*PER;
  if(i0>=DD) return;
  int i1=(i0+PER>DD)?DD:(i0+PER);
  const float* xs=sX+nn*148+O2;
  float x2a[D2],x2b[D2];
  #pragma unroll
  for(int j=0;j<D2;++j){ x2a[j]=xs[2*vp*D2+j]; x2b[j]=xs[(2*vp+1)*D2+j]; }
  for(int idx=i0;idx<i1;++idx){
    int i=idx/D3, k=idx-i*D3;
    float fa=0.f, fb=0.f;
    #pragma unroll
    for(int j=0;j<D2;++j){
      float c=cg[(i*D2+j)*D3+k];
      fa+=c*x2a[j]; fb+=c*x2b[j];
    }
    fa*=scale; fb*=scale;
    aPk[lane*28+idx]=(unsigned int)h16(fa)|((unsigned int)h16(fb)<<16);
  }
}

// phase B: A[row=k*8+n][col-dword=u*8+vp] = packed( sum_i x1[n,u,i]*a[n,v,i,k] ) over v-pair
template<int D1,int D3>
__device__ __forceinline__ void phaseB(const float* __restrict__ sX,
                                       const unsigned int* __restrict__ aPk,
                                       unsigned int* __restrict__ sAu,
                                       int wave, int lane, int nvalid){
  constexpr int O1=(D1==1)?0:((D1==3)?16:64);
  constexpr int DD=D1*D3;
  constexpr int NC=(DD+3)/4;
  const int nn=lane>>3, vp=lane&7;
  if(nn>=nvalid) return;
  unsigned int ar[NC*4];
  const uint4* ap=(const uint4*)(aPk+lane*28);
  #pragma unroll
  for(int c=0;c<NC;++c){ uint4 t=ap[c]; ar[c*4]=t.x; ar[c*4+1]=t.y; ar[c*4+2]=t.z; ar[c*4+3]=t.w; }
  const float* xs=sX+nn*148+O1;
  #pragma unroll
  for(int uu=0;uu<2;++uu){
    int u=wave*2+uu;
    h2 acc[D3];
    #pragma unroll
    for(int k=0;k<D3;++k) acc[k]=(h2){(_Float16)0.f,(_Float16)0.f};
    #pragma unroll
    for(int i=0;i<D1;++i){
      _Float16 xh=(_Float16)xs[u*D1+i];
      h2 xv={xh,xh};
      #pragma unroll
      for(int k=0;k<D3;++k){
        h2 av=__builtin_bit_cast(h2, ar[i*D3+k]);
        acc[k]+=xv*av;
      }
    }
    #pragma unroll
    for(int k=0;k<D3;++k)
      sAu[(k*8+nn)*132+u*8+vp]=__builtin_bit_cast(unsigned int,acc[k]);
  }
}

// stage 2: MFMA; C rows r=Mtile*16+quad*4+reg -> (k=r>>3, node=r&7); stale rows (k>=D3) discarded
template<int L3>
__device__ __forceinline__ void stage2(const unsigned int* __restrict__ sAu,
                                       const unsigned int* __restrict__ sWu,
                                       float* __restrict__ sO,
                                       int wave, int lane){
  constexpr int D3=2*L3+1;
  constexpr int Mtiles=L3+1;
  constexpr int OO=(L3==0)?0:((L3==1)?16:64);
  constexpr int P=Mtiles*3;
  const int n16=lane&15, quad=lane>>4;
  for(int pid=wave;pid<P;pid+=8){
    int tp=pid%3, Mtile=pid/3;
    const unsigned int* ap=sAu+(Mtile*16+n16)*132+quad*4;
    const unsigned int* bp=sWu+tp*2112+n16*132+quad*4;
    f32x4 acc={0.f,0.f,0.f,0.f};
    #pragma unroll
    for(int ks=0;ks<8;++ks){
      half8 af=*reinterpret_cast<const half8*>(ap+ks*16);
      half8 bf=*reinterpret_cast<const half8*>(bp+ks*16);
      acc=__builtin_amdgcn_mfma_f32_16x16x32_f16(af,bf,acc,0,0,0);
    }
    #pragma unroll
    for(int reg=0;reg<4;++reg){
      int row=Mtile*16+quad*4+reg;
      int k=row>>3, node=row&7;
      if(k<D3) sO[node*440+tp*144+OO+n16*D3+k]+=acc[reg];
    }
  }
}

template<int D1,int D2,int D3>
__device__ __forceinline__ void path_body(const float* __restrict__ sX,
    const float* __restrict__ cg, float scale,
    unsigned int* __restrict__ aPk, unsigned int* __restrict__ sAu,
    const unsigned int* __restrict__ sWu, float* __restrict__ sO,
    int wave, int lane, int nvalid){
  phaseA<D1,D2,D3>(sX,cg,scale,aPk,wave,lane,nvalid);
  __syncthreads();
  phaseB<D1,D3>(sX,aPk,sAu,wave,lane,nvalid);
  __syncthreads();
  stage2<(D3-1)/2>(sAu,sWu,sO,wave,lane);
  __syncthreads();
}

__global__ __launch_bounds__(512,4) void tfn_main(
    const unsigned short* __restrict__ xin,
    const unsigned short* __restrict__ wq,
    const unsigned short* __restrict__ wk,
    const unsigned short* __restrict__ wv,
    const unsigned short* __restrict__ wd,
    const float* __restrict__ c3j,
    unsigned short* __restrict__ outp, int N)
{
  __shared__ __align__(16) unsigned int sAu[48*132];   // fp16 A, row stride 132 dwords
  __shared__ __align__(16) unsigned int sWu[3*16*132]; // fp16 W^T per tp: [w][uv-pair]
  __shared__ __align__(16) unsigned int aPk[64*28];    // phase-A a, fp16 v-pairs, per (n,vp)
  __shared__ float sO[NN*440];
  __shared__ float sX[NN*148];
  __shared__ float sWd[768];
  __shared__ float sCdot[36];

  const int tid=threadIdx.x;
  const int wave=tid>>6, lane=tid&63;
  const int node0=blockIdx.x*NN;
  const int nvalid=(N-node0)<NN?(N-node0):NN;

  const int xf32 = c3j[363]!=0.0f;
  const int qf32 = c3j[364]!=0.0f;
  const int kf32 = c3j[365]!=0.0f;
  const int vf32 = c3j[366]!=0.0f;
  const int df32 = c3j[367]!=0.0f;

  // stage x
  if(!xf32){
    for(int t=tid;t<NN*36;t+=512){
      int nn=t/36, w4=t%36;
      if(nn<nvalid){
        uint2 u=((const uint2*)(xin+(size_t)(node0+nn)*144))[w4];
        float* dst=&sX[nn*148+w4*4];
        dst[0]=bfu(u.x&0xffffu); dst[1]=bfu(u.x>>16);
        dst[2]=bfu(u.y&0xffffu); dst[3]=bfu(u.y>>16);
      }
    }
  }else{
    const float* xf=(const float*)xin;
    for(int t=tid;t<NN*144;t+=512){
      int nn=t/144, f=t%144;
      if(nn<nvalid) sX[nn*148+f]=xf[(size_t)(node0+nn)*144+f];
    }
  }
  if(!df32){ for(int t=tid;t<768;t+=512) sWd[t]=bfu((unsigned int)wd[t]); }
  else     { const float* wdf=(const float*)wd; for(int t=tid;t<768;t+=512) sWd[t]=wdf[t]; }
  for(int t=tid;t<35;t+=512) sCdot[t]=c3j[t];
  for(int t=tid;t<NN*440;t+=512) sO[t]=0.f;
  __syncthreads();

  const float scl[3]={0.03608439182435161f,0.05412658773652741f,0.06987712429686843f};

  for(int p=0;p<NP;++p){
    const int l3=g_l3[p];
    // ---- stage weights: [tp][w][uv-pair] fp16 ----
    for(int t=tid;t<1536;t+=512){
      int tp=t>>9, g=t&511, uvp=g>>2, wg=g&3, uv=uvp<<1;
      float f0[4],f1[4];
      const int f32=(tp==0)?qf32:((tp==1)?kf32:vf32);
      const unsigned short* ww=(tp==0)?wq:((tp==1)?wk:wv);
      if(!f32){
        const unsigned short* wwp=ww+(size_t)p*4096;
        uint2 e0=*(const uint2*)(wwp+uv*16+wg*4);
        uint2 e1=*(const uint2*)(wwp+(uv+1)*16+wg*4);
        f0[0]=bfu(e0.x&0xffffu); f0[1]=bfu(e0.x>>16); f0[2]=bfu(e0.y&0xffffu); f0[3]=bfu(e0.y>>16);
        f1[0]=bfu(e1.x&0xffffu); f1[1]=bfu(e1.x>>16); f1[2]=bfu(e1.y&0xffffu); f1[3]=bfu(e1.y>>16);
      }else{
        const float* wwf=(const float*)ww+(size_t)p*4096;
        float4 a0=((const float4*)wwf)[uv*4+wg];
        float4 a1=((const float4*)wwf)[(uv+1)*4+wg];
        f0[0]=a0.x;f0[1]=a0.y;f0[2]=a0.z;f0[3]=a0.w;
        f1[0]=a1.x;f1[1]=a1.y;f1[2]=a1.z;f1[3]=a1.w;
      }
      #pragma unroll
      for(int i=0;i<4;++i){
        unsigned int pk=(unsigned int)h16(f0[i]) | ((unsigned int)h16(f1[i])<<16);
        sWu[tp*2112+(wg*4+i)*132+uvp]=pk;
      }
    }
    const float* cg=c3j+g_coff[p];
    const float sc_=scl[l3];
    switch(p){
      case 0: path_body<1,1,1>(sX,cg,sc_,aPk,sAu,sWu,sO,wave,lane,nvalid); break;
      case 1: path_body<3,3,1>(sX,cg,sc_,aPk,sAu,sWu,sO,wave,lane,nvalid); break;
      case 2: path_body<5,5,1>(sX,cg,sc_,aPk,sAu,sWu,sO,wave,lane,nvalid); break;
      case 3: path_body<1,3,3>(sX,cg,sc_,aPk,sAu,sWu,sO,wave,lane,nvalid); break;
      case 4: path_body<3,1,3>(sX,cg,sc_,aPk,sAu,sWu,sO,wave,lane,nvalid); break;
      case 5: path_body<3,5,3>(sX,cg,sc_,aPk,sAu,sWu,sO,wave,lane,nvalid); break;
      case 6: path_body<5,3,3>(sX,cg,sc_,aPk,sAu,sWu,sO,wave,lane,nvalid); break;
      case 7: path_body<1,5,5>(sX,cg,sc_,aPk,sAu,sWu,sO,wave,lane,nvalid); break;
      case 8: path_body<3,3,5>(sX,cg,sc_,aPk,sAu,sWu,sO,wave,lane,nvalid); break;
      case 9: path_body<5,1,5>(sX,cg,sc_,aPk,sAu,sWu,sO,wave,lane,nvalid); break;
      default: path_body<5,5,5>(sX,cg,sc_,aPk,sAu,sWu,sO,wave,lane,nvalid); break;
    }
  }

  // ---- epilogue: dot, attention, elu, store (one node per wave) ----
  {
    int node=wave;
    if(node<nvalid){
      const float* qv=sO+node*440;
      const float* kv=qv+144;
      float part=0.f;
      #pragma unroll
      for(int t=0;t<4;++t){
        int pq=lane+(t<<6);
        int u=pq>>4, v=pq&15;
        float s3=sWd[u*16+v]*(sCdot[0]*qv[u]*kv[v]);
        float t1=0.f;
        #pragma unroll
        for(int i=0;i<3;++i)
          #pragma unroll
          for(int j=0;j<3;++j)
            t1+=qv[16+u*3+i]*sCdot[1+i*3+j]*kv[16+v*3+j];
        s3+=sWd[256+u*16+v]*t1;
        float t2=0.f;
        #pragma unroll
        for(int i=0;i<5;++i)
          #pragma unroll
          for(int j=0;j<5;++j)
            t2+=qv[64+u*5+i]*sCdot[10+i*5+j]*kv[64+v*5+j];
        s3+=sWd[512+u*16+v]*t2;
        part+=s3;
      }
      #pragma unroll
      for(int off=1;off<64;off<<=1) part+=__shfl_xor(part,off,64);
      float dd=part*0.03608439182435161f;
      float ex=dd*(1.0f/12.0f);
      ex=fminf(fmaxf(ex,-80.f),80.f);
      float e=expf(ex);
      float attn=e/(e+1e-10f);
      const float* vv=sO+node*440+288;
      if(!xf32){
        unsigned short* ob=outp+(size_t)(node0+node)*144;
        for(int f=lane;f<144;f+=64){
          float val=attn*vv[f];
          float r=(val>0.f)?val:expm1f(val);
          ob[f]=(unsigned short)rne16(r);
        }
      }else{
        float* ob=(float*)outp+(size_t)(node0+node)*144;
        for(int f=lane;f<144;f+=64){
          float val=attn*vv[f];
          ob[f]=(val>0.f)?val:expm1f(val);
        }
      }
    }
  }
}

extern "C" void kernel_launch(void* const* d_in, const int* in_sizes, int n_in,
                              void* d_out, int out_size, void* d_ws, size_t ws_size,
                              hipStream_t stream){
  (void)n_in; (void)out_size; (void)ws_size;
  const unsigned short* x =(const unsigned short*)d_in[0];
  const unsigned short* wq=(const unsigned short*)d_in[4];
  const unsigned short* wk=(const unsigned short*)d_in[5];
  const unsigned short* wv=(const unsigned short*)d_in[6];
  const unsigned short* wd=(const unsigned short*)d_in[7];
  float* c3j=(float*)d_ws;                      // [0..362] w3j, [363..367] dtype flags
  int N=in_sizes[0]/144;
  w3j_init<<<dim3(NP),dim3(128),0,stream>>>(c3j);
  dtype_probe<<<dim3(1),dim3(256),0,stream>>>(x ,in_sizes[0],c3j+363);
  dtype_probe<<<dim3(1),dim3(256),0,stream>>>(wq,in_sizes[4],c3j+364);
  dtype_probe<<<dim3(1),dim3(256),0,stream>>>(wk,in_sizes[5],c3j+365);
  dtype_probe<<<dim3(1),dim3(256),0,stream>>>(wv,in_sizes[6],c3j+366);
  dtype_probe<<<dim3(1),dim3(256),0,stream>>>(wd,in_sizes[7],c3j+367);
  int nb=(N+NN-1)/NN;
  tfn_main<<<dim3(nb),dim3(512),0,stream>>>(x,wq,wk,wv,wd,c3j,(unsigned short*)d_out,N);
}

// Round 5
// 441.321 us; speedup vs baseline: 10.4862x; 1.2665x over previous
//
#include <hip/hip_runtime.h>
#include <math.h>

#define NP 11
#define NN 8    // nodes per block (512 threads, 8 waves)

__device__ __constant__ int g_l1[NP]   = {0,1,2,0,1,1,2,0,1,2,2};
__device__ __constant__ int g_l2[NP]   = {0,1,2,1,0,2,1,2,1,0,2};
__device__ __constant__ int g_l3[NP]   = {0,0,0,1,1,1,1,2,2,2,2};
__device__ __constant__ int g_coff[NP] = {0,1,10,35,44,53,98,143,168,213,238};

typedef _Float16 half8 __attribute__((ext_vector_type(8)));
typedef _Float16 h2 __attribute__((ext_vector_type(2)));
typedef float f32x4 __attribute__((ext_vector_type(4)));

// ---------------- Wigner-3j precompute (exact replica of reference, fp64) ----------------
__device__ double dfact(int n){ double r=1.0; for(int i=2;i<=n;++i) r*=(double)i; return r; }

__device__ double su2_cg(int j1,int m1,int j2,int m2,int j3,int m3){
  if(m1+m2!=m3) return 0.0;
  int vmin=-j1+j2+m3; if(-j1+m1>vmin) vmin=-j1+m1; if(vmin<0) vmin=0;
  int vmax=j2+j3+m1; int t=j3-j1+j2; if(t<vmax) vmax=t; t=j3+m3; if(t<vmax) vmax=t;
  double C = sqrt((double)(2*j3+1)*dfact(j3+j1-j2)*dfact(j3-j1+j2)*dfact(j1+j2-j3)
      *dfact(j3+m3)*dfact(j3-m3)
      /(dfact(j1+j2+j3+1)*dfact(j1-m1)*dfact(j1+m1)*dfact(j2-m2)*dfact(j2+m2)));
  double S=0.0;
  for(int v=vmin;v<=vmax;++v){
    double sg = ((v+j2+m2)&1)? -1.0:1.0;
    S += sg*dfact(j2+j3+m1-v)*dfact(j1-m1+v)
        /(dfact(v)*dfact(j3-j1+j2-v)*dfact(j3+m3-v)*dfact(v+j1-j2-m3));
  }
  return C*S;
}

__device__ void qelem(int l,int r,int c,double &re,double &im){
  int m=r-l; double a=0.0,b=0.0; const double s=0.70710678118654752440;
  if(m<0){ if(c==l-m) a=s; else if(c==l+m) b=-s; }
  else if(m==0){ if(c==l) a=1.0; }
  else { double sg=(m&1)?-1.0:1.0; if(c==l+m) a=sg*s; else if(c==l-m) b=sg*s; }
  if(l==1){ double tt=a; a=b; b=-tt; }
  else if(l==2){ a=-a; b=-b; }
  re=a; im=b;
}

__global__ void w3j_init(float* __restrict__ ws){
  int p=blockIdx.x;
  int l1=g_l1[p], l2=g_l2[p], l3=g_l3[p];
  int d1=2*l1+1, d2=2*l2+1, d3=2*l3+1;
  int tot=d1*d2*d3;
  __shared__ double cg[125];
  __shared__ double outv[125];
  __shared__ double nrm;
  for(int t=threadIdx.x;t<tot;t+=blockDim.x){
    int i=t/(d2*d3), k=(t/d3)%d2, n=t%d3;
    cg[t]=su2_cg(l1,i-l1,l2,k-l2,l3,n-l3);
  }
  __syncthreads();
  for(int t=threadIdx.x;t<tot;t+=blockDim.x){
    int a=t/(d2*d3), b=(t/d3)%d2, c=t%d3;
    double sre=0.0;
    for(int i=0;i<d1;++i){ double q1r,q1i; qelem(l1,i,a,q1r,q1i);
      for(int k=0;k<d2;++k){ double q2r,q2i; qelem(l2,k,b,q2r,q2i);
        double pr=q1r*q2r-q1i*q2i, pi=q1r*q2i+q1i*q2r;
        for(int n=0;n<d3;++n){ double q3r,q3i; qelem(l3,n,c,q3r,q3i);
          sre += (pr*q3r + pi*q3i) * cg[(i*d2+k)*d3+n];
        }
      }
    }
    outv[t]=sre;
  }
  __syncthreads();
  if(threadIdx.x==0){
    double s=0.0; for(int t=0;t<tot;++t) s+=outv[t]*outv[t];
    nrm=sqrt(s);
  }
  __syncthreads();
  for(int t=threadIdx.x;t<tot;t+=blockDim.x)
    ws[g_coff[p]+t]=(float)(outv[t]/nrm);
}

// ---------------- dtype probes (merged into one launch, 5 blocks) ----------------
__global__ void dtype_probe5(const unsigned short* p0,const unsigned short* p1,
                             const unsigned short* p2,const unsigned short* p3,
                             const unsigned short* p4,
                             int n0,int n1,int n2,int n3,int n4,
                             float* __restrict__ flags){
  __shared__ int cnt;
  const unsigned short* ps[5]={p0,p1,p2,p3,p4};
  int ns[5]={n0,n1,n2,n3,n4};
  int b=blockIdx.x;
  const unsigned short* p=ps[b]; int nelem=ns[b];
  if(threadIdx.x==0) cnt=0;
  __syncthreads();
  int M = nelem < 4096 ? nelem : 4096;
  int c=0;
  for(int t=threadIdx.x;t<M;t+=blockDim.x){
    unsigned e=((unsigned)p[t]>>7)&0xFFu;
    if(e!=0u && (e<0x70u || e>0x8Eu)) ++c;
  }
  atomicAdd(&cnt,c);
  __syncthreads();
  if(threadIdx.x==0) flags[b] = (cnt*8 > M) ? 1.0f : 0.0f;
}

// ---------------- helpers ----------------
__device__ __forceinline__ float bfu(unsigned int v){ return __uint_as_float(v<<16); }
__device__ __forceinline__ unsigned int rne16(float f){
  unsigned int ui=__float_as_uint(f);
  return (ui+0x7fffu+((ui>>16)&1u))>>16;
}
__device__ __forceinline__ unsigned short h16(float f){
  _Float16 h=(_Float16)f;
  return __builtin_bit_cast(unsigned short,h);
}

// ---------------- weight pre-transpose (one-time): exact sWu LDS image per path ----------------
// wpre[(p*3+tp)*2112 + w*132 + uvp] = pack_fp16(W[2uvp][w], W[2uvp+1][w]),  W[uv][w]=w_in[p][u][v][w]
__global__ void w_prep(const unsigned short* __restrict__ wq,
                       const unsigned short* __restrict__ wk,
                       const unsigned short* __restrict__ wv,
                       const float* __restrict__ flags,   // c3j+364: {wq,wk,wv}
                       unsigned int* __restrict__ wpre){
  int p=blockIdx.x, tp=blockIdx.y;
  const unsigned short* ww=(tp==0)?wq:((tp==1)?wk:wv);
  int f32=flags[tp]!=0.0f;
  unsigned int* dst=wpre+(size_t)(p*3+tp)*2112;
  for(int t=threadIdx.x;t<2048;t+=256){
    int w=t>>7, uvp=t&127;
    float f0,f1;
    if(f32){
      const float* wf=(const float*)ww+(size_t)p*4096;
      f0=wf[(2*uvp)*16+w]; f1=wf[(2*uvp+1)*16+w];
    }else{
      const unsigned short* wsp=ww+(size_t)p*4096;
      f0=bfu(wsp[(2*uvp)*16+w]); f1=bfu(wsp[(2*uvp+1)*16+w]);
    }
    dst[w*132+uvp]=(unsigned int)h16(f0)|((unsigned int)h16(f1)<<16);
  }
}

// phase A: a[lane=(n,vp)][idx=(i*D3+k)] = scale * sum_j C[ijk]*x2[n,2vp+{0,1},j]  (fp16 pair)
template<int D1,int D2,int D3>
__device__ __forceinline__ void phaseA(const float* __restrict__ sX,
                                       const float* __restrict__ cg, float scale,
                                       unsigned int* __restrict__ aPk,
                                       int wave, int lane, int nvalid){
  constexpr int O2=(D2==1)?0:((D2==3)?16:64);
  constexpr int DD=D1*D3;
  constexpr int PER=(DD+7)>>3;
  const int nn=lane>>3, vp=lane&7;
  if(nn>=nvalid) return;
  int i0=wave*PER;
  if(i0>=DD) return;
  int i1=(i0+PER>DD)?DD:(i0+PER);
  const float* xs=sX+nn*148+O2;
  float x2a[D2],x2b[D2];
  #pragma unroll
  for(int j=0;j<D2;++j){ x2a[j]=xs[2*vp*D2+j]; x2b[j]=xs[(2*vp+1)*D2+j]; }
  for(int idx=i0;idx<i1;++idx){
    int i=idx/D3, k=idx-i*D3;
    float fa=0.f, fb=0.f;
    #pragma unroll
    for(int j=0;j<D2;++j){
      float c=cg[(i*D2+j)*D3+k];
      fa+=c*x2a[j]; fb+=c*x2b[j];
    }
    fa*=scale; fb*=scale;
    aPk[lane*28+idx]=(unsigned int)h16(fa)|((unsigned int)h16(fb)<<16);
  }
}

// phase B: A[row=k*8+n][col-dword=u*8+vp] = packed( sum_i x1[n,u,i]*a[n,v,i,k] ) over v-pair
template<int D1,int D3>
__device__ __forceinline__ void phaseB(const float* __restrict__ sX,
                                       const unsigned int* __restrict__ aPk,
                                       unsigned int* __restrict__ sAu,
                                       int wave, int lane, int nvalid){
  constexpr int O1=(D1==1)?0:((D1==3)?16:64);
  constexpr int DD=D1*D3;
  constexpr int NC=(DD+3)/4;
  const int nn=lane>>3, vp=lane&7;
  if(nn>=nvalid) return;
  unsigned int ar[NC*4];
  const uint4* ap=(const uint4*)(aPk+lane*28);
  #pragma unroll
  for(int c=0;c<NC;++c){ uint4 t=ap[c]; ar[c*4]=t.x; ar[c*4+1]=t.y; ar[c*4+2]=t.z; ar[c*4+3]=t.w; }
  const float* xs=sX+nn*148+O1;
  #pragma unroll
  for(int uu=0;uu<2;++uu){
    int u=wave*2+uu;
    h2 acc[D3];
    #pragma unroll
    for(int k=0;k<D3;++k) acc[k]=(h2){(_Float16)0.f,(_Float16)0.f};
    #pragma unroll
    for(int i=0;i<D1;++i){
      _Float16 xh=(_Float16)xs[u*D1+i];
      h2 xv={xh,xh};
      #pragma unroll
      for(int k=0;k<D3;++k){
        h2 av=__builtin_bit_cast(h2, ar[i*D3+k]);
        acc[k]+=xv*av;
      }
    }
    #pragma unroll
    for(int k=0;k<D3;++k)
      sAu[(k*8+nn)*132+u*8+vp]=__builtin_bit_cast(unsigned int,acc[k]);
  }
}

// stage 2: MFMA, accumulate in registers across paths of the same l3 group.
// pid ownership fixed: pid = wave (+8). C rows r=Mtile*16+quad*4+reg -> (k=r>>3, node=r&7)
template<int L3>
__device__ __forceinline__ void stage2_acc(const unsigned int* __restrict__ sAu,
                                           const unsigned int* __restrict__ sWu,
                                           f32x4& a0, f32x4& a1,
                                           int n16, int quad, int wave){
  constexpr int P=(L3+1)*3;
  {
    int pid=wave;
    if(pid<P){
      int tp=pid%3, Mt=pid/3;
      const unsigned int* ap=sAu+(Mt*16+n16)*132+quad*4;
      const unsigned int* bp=sWu+tp*2112+n16*132+quad*4;
      f32x4 a=a0;
      #pragma unroll
      for(int ks=0;ks<8;++ks)
        a=__builtin_amdgcn_mfma_f32_16x16x32_f16(
            *reinterpret_cast<const half8*>(ap+ks*16),
            *reinterpret_cast<const half8*>(bp+ks*16),a,0,0,0);
      a0=a;
    }
  }
  if(P>8){
    int pid=wave+8;
    if(pid<P){
      int tp=pid%3, Mt=pid/3;
      const unsigned int* ap=sAu+(Mt*16+n16)*132+quad*4;
      const unsigned int* bp=sWu+tp*2112+n16*132+quad*4;
      f32x4 a=a1;
      #pragma unroll
      for(int ks=0;ks<8;++ks)
        a=__builtin_amdgcn_mfma_f32_16x16x32_f16(
            *reinterpret_cast<const half8*>(ap+ks*16),
            *reinterpret_cast<const half8*>(bp+ks*16),a,0,0,0);
      a1=a;
    }
  }
}

template<int L3>
__device__ __forceinline__ void stage2_out(const f32x4& a0, const f32x4& a1,
                                           float* __restrict__ sO,
                                           int n16, int quad, int wave){
  constexpr int D3=2*L3+1;
  constexpr int OO=(L3==0)?0:((L3==1)?16:64);
  constexpr int P=(L3+1)*3;
  {
    int pid=wave;
    if(pid<P){
      int tp=pid%3, Mt=pid/3;
      #pragma unroll
      for(int reg=0;reg<4;++reg){
        int row=Mt*16+quad*4+reg;
        int k=row>>3, node=row&7;
        if(k<D3) sO[node*440+tp*144+OO+n16*D3+k]=a0[reg];
      }
    }
  }
  if(P>8){
    int pid=wave+8;
    if(pid<P){
      int tp=pid%3, Mt=pid/3;
      #pragma unroll
      for(int reg=0;reg<4;++reg){
        int row=Mt*16+quad*4+reg;
        int k=row>>3, node=row&7;
        if(k<D3) sO[node*440+tp*144+OO+n16*D3+k]=a1[reg];
      }
    }
  }
}

__global__ __launch_bounds__(512,4) void tfn_main(
    const unsigned short* __restrict__ xin,
    const unsigned int* __restrict__ wpre,
    const unsigned short* __restrict__ wd,
    const float* __restrict__ c3j,
    unsigned short* __restrict__ outp, int N)
{
  __shared__ __align__(16) unsigned int sAu[48*132];   // fp16 A, row stride 132 dwords
  __shared__ __align__(16) unsigned int sWu[3*16*132]; // fp16 W^T image for current path
  __shared__ __align__(16) unsigned int aPk[64*28];    // phase-A a, fp16 v-pairs
  __shared__ float sO[NN*440];
  __shared__ float sX[NN*148];
  __shared__ float sWd[768];

  const int tid=threadIdx.x;
  const int wave=tid>>6, lane=tid&63;
  const int n16=lane&15, quad=lane>>4;
  const int node0=blockIdx.x*NN;
  const int nvalid=(N-node0)<NN?(N-node0):NN;

  const int xf32 = c3j[363]!=0.0f;
  const int df32 = c3j[367]!=0.0f;

  // stage x
  if(!xf32){
    for(int t=tid;t<NN*36;t+=512){
      int nn=t/36, w4=t%36;
      if(nn<nvalid){
        uint2 u=((const uint2*)(xin+(size_t)(node0+nn)*144))[w4];
        float* dst=&sX[nn*148+w4*4];
        dst[0]=bfu(u.x&0xffffu); dst[1]=bfu(u.x>>16);
        dst[2]=bfu(u.y&0xffffu); dst[3]=bfu(u.y>>16);
      }
    }
  }else{
    const float* xf=(const float*)xin;
    for(int t=tid;t<NN*144;t+=512){
      int nn=t/144, f=t%144;
      if(nn<nvalid) sX[nn*148+f]=xf[(size_t)(node0+nn)*144+f];
    }
  }
  if(!df32){ for(int t=tid;t<768;t+=512) sWd[t]=bfu((unsigned int)wd[t]); }
  else     { const float* wdf=(const float*)wd; for(int t=tid;t<768;t+=512) sWd[t]=wdf[t]; }
  __syncthreads();

  const float scl[3]={0.03608439182435161f,0.05412658773652741f,0.06987712429686843f};

  // one path step: stage weights (bulk copy), phaseA, phaseB, MFMA-accumulate
  #define PATH_STEP(P_,D1_,D2_,D3_) { \
    const uint4* wsrc=(const uint4*)(wpre+(size_t)P_*6336); \
    for(int t=tid;t<1584;t+=512) ((uint4*)sWu)[t]=wsrc[t]; \
    phaseA<D1_,D2_,D3_>(sX,c3j+g_coff[P_],scl[(D3_-1)/2],aPk,wave,lane,nvalid); \
    __syncthreads(); \
    phaseB<D1_,D3_>(sX,aPk,sAu,wave,lane,nvalid); \
    __syncthreads(); \
    stage2_acc<(D3_-1)/2>(sAu,sWu,a0,a1,n16,quad,wave); \
    __syncthreads(); }

  { // group l3=0: paths 0,1,2
    f32x4 a0={0.f,0.f,0.f,0.f}, a1={0.f,0.f,0.f,0.f};
    PATH_STEP(0,1,1,1)
    PATH_STEP(1,3,3,1)
    PATH_STEP(2,5,5,1)
    stage2_out<0>(a0,a1,sO,n16,quad,wave);
  }
  { // group l3=1: paths 3,4,5,6
    f32x4 a0={0.f,0.f,0.f,0.f}, a1={0.f,0.f,0.f,0.f};
    PATH_STEP(3,1,3,3)
    PATH_STEP(4,3,1,3)
    PATH_STEP(5,3,5,3)
    PATH_STEP(6,5,3,3)
    stage2_out<1>(a0,a1,sO,n16,quad,wave);
  }
  { // group l3=2: paths 7,8,9,10
    f32x4 a0={0.f,0.f,0.f,0.f}, a1={0.f,0.f,0.f,0.f};
    PATH_STEP(7,1,5,5)
    PATH_STEP(8,3,3,5)
    PATH_STEP(9,5,1,5)
    PATH_STEP(10,5,5,5)
    stage2_out<2>(a0,a1,sO,n16,quad,wave);
  }
  #undef PATH_STEP
  __syncthreads();

  // ---- epilogue: dot via C(l,l,0)=c_l*I (invariant bilinear form on real irrep) ----
  {
    int node=wave;
    if(node<nvalid){
      const float c0=c3j[0], c1=c3j[1], c2=c3j[10];   // diagonal values from exact table
      const float* qv=sO+node*440;
      const float* kv=qv+144;
      const int v=lane&15, ug=lane>>4;
      float k0=kv[v];
      float k1[3],k2[5];
      #pragma unroll
      for(int j=0;j<3;++j) k1[j]=kv[16+v*3+j];
      #pragma unroll
      for(int m=0;m<5;++m) k2[m]=kv[64+v*5+m];
      float part=0.f;
      #pragma unroll
      for(int t=0;t<4;++t){
        int u=ug+4*t;
        float d0=qv[u]*k0;
        float d1=0.f;
        #pragma unroll
        for(int j=0;j<3;++j) d1+=qv[16+u*3+j]*k1[j];
        float d2=0.f;
        #pragma unroll
        for(int m=0;m<5;++m) d2+=qv[64+u*5+m]*k2[m];
        part+=sWd[u*16+v]*(c0*d0)+sWd[256+u*16+v]*(c1*d1)+sWd[512+u*16+v]*(c2*d2);
      }
      #pragma unroll
      for(int off=1;off<64;off<<=1) part+=__shfl_xor(part,off,64);
      float dd=part*0.03608439182435161f;   // * sqrt(1/768)
      float ex=dd*(1.0f/12.0f);             // / sqrt(144)
      ex=fminf(fmaxf(ex,-80.f),80.f);
      float e=expf(ex);
      float attn=e/(e+1e-10f);
      const float* vv=sO+node*440+288;
      if(!xf32){
        unsigned short* ob=outp+(size_t)(node0+node)*144;
        for(int f=lane;f<144;f+=64){
          float val=attn*vv[f];
          float r=(val>0.f)?val:expm1f(val);
          ob[f]=(unsigned short)rne16(r);
        }
      }else{
        float* ob=(float*)outp+(size_t)(node0+node)*144;
        for(int f=lane;f<144;f+=64){
          float val=attn*vv[f];
          ob[f]=(val>0.f)?val:expm1f(val);
        }
      }
    }
  }
}

extern "C" void kernel_launch(void* const* d_in, const int* in_sizes, int n_in,
                              void* d_out, int out_size, void* d_ws, size_t ws_size,
                              hipStream_t stream){
  (void)n_in; (void)out_size; (void)ws_size;
  const unsigned short* x =(const unsigned short*)d_in[0];
  const unsigned short* wq=(const unsigned short*)d_in[4];
  const unsigned short* wk=(const unsigned short*)d_in[5];
  const unsigned short* wv=(const unsigned short*)d_in[6];
  const unsigned short* wd=(const unsigned short*)d_in[7];
  float* c3j=(float*)d_ws;                       // [0..362] w3j, [363..367] dtype flags
  unsigned int* wpre=(unsigned int*)((float*)d_ws+512);  // 11*3*2112 dwords fp16-pair weights
  int N=in_sizes[0]/144;
  w3j_init<<<dim3(NP),dim3(128),0,stream>>>(c3j);
  dtype_probe5<<<dim3(5),dim3(256),0,stream>>>(x,wq,wk,wv,wd,
      in_sizes[0],in_sizes[4],in_sizes[5],in_sizes[6],in_sizes[7],c3j+363);
  w_prep<<<dim3(NP,3),dim3(256),0,stream>>>(wq,wk,wv,c3j+364,wpre);
  int nb=(N+NN-1)/NN;
  tfn_main<<<dim3(nb),dim3(512),0,stream>>>(x,wpre,wd,c3j,(unsigned short*)d_out,N);
}

// Round 6
// 393.117 us; speedup vs baseline: 11.7721x; 1.1226x over previous
//
#include <hip/hip_runtime.h>
#include <math.h>

#define NP 11
#define NN 8    // nodes per block (512 threads, 8 waves)

__device__ __constant__ int g_l1[NP]   = {0,1,2,0,1,1,2,0,1,2,2};
__device__ __constant__ int g_l2[NP]   = {0,1,2,1,0,2,1,2,1,0,2};
__device__ __constant__ int g_l3[NP]   = {0,0,0,1,1,1,1,2,2,2,2};
__device__ __constant__ int g_coff[NP] = {0,1,10,35,44,53,98,143,168,213,238};

typedef _Float16 half8 __attribute__((ext_vector_type(8)));
typedef _Float16 h2 __attribute__((ext_vector_type(2)));
typedef float f32x4 __attribute__((ext_vector_type(4)));

// ---------------- Wigner-3j precompute (exact replica of reference, fp64) ----------------
__device__ double dfact(int n){ double r=1.0; for(int i=2;i<=n;++i) r*=(double)i; return r; }

__device__ double su2_cg(int j1,int m1,int j2,int m2,int j3,int m3){
  if(m1+m2!=m3) return 0.0;
  int vmin=-j1+j2+m3; if(-j1+m1>vmin) vmin=-j1+m1; if(vmin<0) vmin=0;
  int vmax=j2+j3+m1; int t=j3-j1+j2; if(t<vmax) vmax=t; t=j3+m3; if(t<vmax) vmax=t;
  double C = sqrt((double)(2*j3+1)*dfact(j3+j1-j2)*dfact(j3-j1+j2)*dfact(j1+j2-j3)
      *dfact(j3+m3)*dfact(j3-m3)
      /(dfact(j1+j2+j3+1)*dfact(j1-m1)*dfact(j1+m1)*dfact(j2-m2)*dfact(j2+m2)));
  double S=0.0;
  for(int v=vmin;v<=vmax;++v){
    double sg = ((v+j2+m2)&1)? -1.0:1.0;
    S += sg*dfact(j2+j3+m1-v)*dfact(j1-m1+v)
        /(dfact(v)*dfact(j3-j1+j2-v)*dfact(j3+m3-v)*dfact(v+j1-j2-m3));
  }
  return C*S;
}

__device__ void qelem(int l,int r,int c,double &re,double &im){
  int m=r-l; double a=0.0,b=0.0; const double s=0.70710678118654752440;
  if(m<0){ if(c==l-m) a=s; else if(c==l+m) b=-s; }
  else if(m==0){ if(c==l) a=1.0; }
  else { double sg=(m&1)?-1.0:1.0; if(c==l+m) a=sg*s; else if(c==l-m) b=sg*s; }
  if(l==1){ double tt=a; a=b; b=-tt; }
  else if(l==2){ a=-a; b=-b; }
  re=a; im=b;
}

__global__ void w3j_init(float* __restrict__ ws){
  int p=blockIdx.x;
  int l1=g_l1[p], l2=g_l2[p], l3=g_l3[p];
  int d1=2*l1+1, d2=2*l2+1, d3=2*l3+1;
  int tot=d1*d2*d3;
  __shared__ double cg[125];
  __shared__ double outv[125];
  __shared__ double nrm;
  for(int t=threadIdx.x;t<tot;t+=blockDim.x){
    int i=t/(d2*d3), k=(t/d3)%d2, n=t%d3;
    cg[t]=su2_cg(l1,i-l1,l2,k-l2,l3,n-l3);
  }
  __syncthreads();
  for(int t=threadIdx.x;t<tot;t+=blockDim.x){
    int a=t/(d2*d3), b=(t/d3)%d2, c=t%d3;
    double sre=0.0;
    for(int i=0;i<d1;++i){ double q1r,q1i; qelem(l1,i,a,q1r,q1i);
      for(int k=0;k<d2;++k){ double q2r,q2i; qelem(l2,k,b,q2r,q2i);
        double pr=q1r*q2r-q1i*q2i, pi=q1r*q2i+q1i*q2r;
        for(int n=0;n<d3;++n){ double q3r,q3i; qelem(l3,n,c,q3r,q3i);
          sre += (pr*q3r + pi*q3i) * cg[(i*d2+k)*d3+n];
        }
      }
    }
    outv[t]=sre;
  }
  __syncthreads();
  if(threadIdx.x==0){
    double s=0.0; for(int t=0;t<tot;++t) s+=outv[t]*outv[t];
    nrm=sqrt(s);
  }
  __syncthreads();
  for(int t=threadIdx.x;t<tot;t+=blockDim.x)
    ws[g_coff[p]+t]=(float)(outv[t]/nrm);
}

// ---------------- dtype probes (one launch, 5 blocks) ----------------
__global__ void dtype_probe5(const unsigned short* p0,const unsigned short* p1,
                             const unsigned short* p2,const unsigned short* p3,
                             const unsigned short* p4,
                             int n0,int n1,int n2,int n3,int n4,
                             float* __restrict__ flags){
  __shared__ int cnt;
  const unsigned short* ps[5]={p0,p1,p2,p3,p4};
  int ns[5]={n0,n1,n2,n3,n4};
  int b=blockIdx.x;
  const unsigned short* p=ps[b]; int nelem=ns[b];
  if(threadIdx.x==0) cnt=0;
  __syncthreads();
  int M = nelem < 4096 ? nelem : 4096;
  int c=0;
  for(int t=threadIdx.x;t<M;t+=blockDim.x){
    unsigned e=((unsigned)p[t]>>7)&0xFFu;
    if(e!=0u && (e<0x70u || e>0x8Eu)) ++c;
  }
  atomicAdd(&cnt,c);
  __syncthreads();
  if(threadIdx.x==0) flags[b] = (cnt*8 > M) ? 1.0f : 0.0f;
}

// ---------------- helpers ----------------
__device__ __forceinline__ float bfu(unsigned int v){ return __uint_as_float(v<<16); }
__device__ __forceinline__ unsigned int rne16(float f){
  unsigned int ui=__float_as_uint(f);
  return (ui+0x7fffu+((ui>>16)&1u))>>16;
}
__device__ __forceinline__ unsigned short h16(float f){
  _Float16 h=(_Float16)f;
  return __builtin_bit_cast(unsigned short,h);
}

// ---------------- weight pre-transpose (one-time): fp16 W^T, stride-140 rows ----------------
// wpre[(p*3+tp)*2240 + w*140 + uvp] = pack_fp16(W[2uvp][w], W[2uvp+1][w])
__global__ void w_prep(const unsigned short* __restrict__ wq,
                       const unsigned short* __restrict__ wk,
                       const unsigned short* __restrict__ wv,
                       const float* __restrict__ flags,   // c3j+364: {wq,wk,wv}
                       unsigned int* __restrict__ wpre){
  int p=blockIdx.x, tp=blockIdx.y;
  const unsigned short* ww=(tp==0)?wq:((tp==1)?wk:wv);
  int f32=flags[tp]!=0.0f;
  unsigned int* dst=wpre+(size_t)(p*3+tp)*2240;
  for(int t=threadIdx.x;t<2048;t+=256){
    int w=t>>7, uvp=t&127;
    float f0,f1;
    if(f32){
      const float* wf=(const float*)ww+(size_t)p*4096;
      f0=wf[(2*uvp)*16+w]; f1=wf[(2*uvp+1)*16+w];
    }else{
      const unsigned short* wsp=ww+(size_t)p*4096;
      f0=bfu(wsp[(2*uvp)*16+w]); f1=bfu(wsp[(2*uvp+1)*16+w]);
    }
    dst[w*140+uvp]=(unsigned int)h16(f0)|((unsigned int)h16(f1)<<16);
  }
}

// ---------------- fused stage 1 (phaseA+phaseB, no intermediate LDS) ----------------
// A[row=k*8+n][col-dword=u*8+vp] = packed over v-pair of sum_i x1[u,i] * (scale*sum_j C[ijk] x2[v,j])
template<int D1,int D2,int D3>
__device__ __forceinline__ void fusedAB(const float* __restrict__ sX,
                                        const float* __restrict__ cg, float scale,
                                        unsigned int* __restrict__ sAu,
                                        int wave, int lane, int nvalid){
  constexpr int O1=(D1==1)?0:((D1==3)?16:64);
  constexpr int O2=(D2==1)?0:((D2==3)?16:64);
  const int nn=lane>>3, vp=lane&7;
  if(nn>=nvalid) return;
  const float* xb=sX+nn*148;
  float x2a[D2],x2b[D2];
  #pragma unroll
  for(int j=0;j<D2;++j){
    x2a[j]=xb[O2+2*vp*D2+j]*scale;
    x2b[j]=xb[O2+(2*vp+1)*D2+j]*scale;
  }
  const int u0=wave*2;
  _Float16 x1a[D1],x1b[D1];
  #pragma unroll
  for(int i=0;i<D1;++i){
    x1a[i]=(_Float16)xb[O1+u0*D1+i];
    x1b[i]=(_Float16)xb[O1+(u0+1)*D1+i];
  }
  h2 acc0[D3],acc1[D3];
  #pragma unroll
  for(int k=0;k<D3;++k){ acc0[k]=(h2){(_Float16)0.f,(_Float16)0.f}; acc1[k]=acc0[k]; }
  #pragma unroll
  for(int i=0;i<D1;++i){
    h2 hva={x1a[i],x1a[i]}, hvb={x1b[i],x1b[i]};
    #pragma unroll
    for(int k=0;k<D3;++k){
      float fa=0.f,fb=0.f;
      #pragma unroll
      for(int j=0;j<D2;++j){
        float c=cg[(i*D2+j)*D3+k];
        fa+=c*x2a[j]; fb+=c*x2b[j];
      }
      h2 ar={(_Float16)fa,(_Float16)fb};
      acc0[k]+=hva*ar;
      acc1[k]+=hvb*ar;
    }
  }
  #pragma unroll
  for(int k=0;k<D3;++k){
    sAu[(k*8+nn)*140+u0*8+vp]    =__builtin_bit_cast(unsigned int,acc0[k]);
    sAu[(k*8+nn)*140+(u0+1)*8+vp]=__builtin_bit_cast(unsigned int,acc1[k]);
  }
}

// ---------------- stage 2: MFMA, A from LDS (stride 140, conflict-free), B from global/L2 ----------------
template<int L3>
__device__ __forceinline__ void stage2_acc(const unsigned int* __restrict__ sAu,
                                           const unsigned int* __restrict__ wp_path,
                                           f32x4& a0, f32x4& a1,
                                           int n16, int quad, int wave){
  constexpr int P=(L3+1)*3;
  if(wave<P){
    int tp=wave%3, Mt=wave/3;
    const unsigned int* ap=sAu+(Mt*16+n16)*140+quad*4;
    const uint4* bp=(const uint4*)(wp_path+tp*2240+n16*140+quad*4);
    uint4 b[8];
    #pragma unroll
    for(int ks=0;ks<8;++ks) b[ks]=bp[ks*4];
    f32x4 a=a0;
    #pragma unroll
    for(int ks=0;ks<8;++ks)
      a=__builtin_amdgcn_mfma_f32_16x16x32_f16(
          *reinterpret_cast<const half8*>(ap+ks*16),
          __builtin_bit_cast(half8,b[ks]),a,0,0,0);
    a0=a;
  }
  if(L3==2 && wave==0){           // pid 8: tp=2, Mt=2
    const unsigned int* ap=sAu+(2*16+n16)*140+quad*4;
    const uint4* bp=(const uint4*)(wp_path+2*2240+n16*140+quad*4);
    uint4 b[8];
    #pragma unroll
    for(int ks=0;ks<8;++ks) b[ks]=bp[ks*4];
    f32x4 a=a1;
    #pragma unroll
    for(int ks=0;ks<8;++ks)
      a=__builtin_amdgcn_mfma_f32_16x16x32_f16(
          *reinterpret_cast<const half8*>(ap+ks*16),
          __builtin_bit_cast(half8,b[ks]),a,0,0,0);
    a1=a;
  }
}

template<int L3>
__device__ __forceinline__ void stage2_out(const f32x4& a0, const f32x4& a1,
                                           float* __restrict__ sO,
                                           int n16, int quad, int wave){
  constexpr int D3=2*L3+1;
  constexpr int OO=(L3==0)?0:((L3==1)?16:64);
  constexpr int P=(L3+1)*3;
  if(wave<P){
    int tp=wave%3, Mt=wave/3;
    #pragma unroll
    for(int reg=0;reg<4;++reg){
      int row=Mt*16+quad*4+reg;
      int k=row>>3, node=row&7;
      if(k<D3) sO[node*440+tp*144+OO+n16*D3+k]=a0[reg];
    }
  }
  if(L3==2 && wave==0){
    #pragma unroll
    for(int reg=0;reg<4;++reg){
      int row=32+quad*4+reg;
      int k=row>>3, node=row&7;
      if(k<D3) sO[node*440+2*144+OO+n16*D3+k]=a1[reg];
    }
  }
}

__global__ __launch_bounds__(512,6) void tfn_main(
    const unsigned short* __restrict__ xin,
    const unsigned int* __restrict__ wpre,
    const unsigned short* __restrict__ wd,
    const float* __restrict__ c3j,
    unsigned short* __restrict__ outp, int N)
{
  __shared__ __align__(16) unsigned int sAu[48*140];   // fp16 A, row stride 140 dwords (2-way max)
  __shared__ float sO[NN*440];
  __shared__ float sX[NN*148];
  __shared__ float sWd[768];

  const int tid=threadIdx.x;
  const int wave=tid>>6, lane=tid&63;
  const int n16=lane&15, quad=lane>>4;
  const int node0=blockIdx.x*NN;
  const int nvalid=(N-node0)<NN?(N-node0):NN;

  const int xf32 = c3j[363]!=0.0f;
  const int df32 = c3j[367]!=0.0f;

  // stage x
  if(!xf32){
    for(int t=tid;t<NN*36;t+=512){
      int nn=t/36, w4=t%36;
      if(nn<nvalid){
        uint2 u=((const uint2*)(xin+(size_t)(node0+nn)*144))[w4];
        float* dst=&sX[nn*148+w4*4];
        dst[0]=bfu(u.x&0xffffu); dst[1]=bfu(u.x>>16);
        dst[2]=bfu(u.y&0xffffu); dst[3]=bfu(u.y>>16);
      }
    }
  }else{
    const float* xf=(const float*)xin;
    for(int t=tid;t<NN*144;t+=512){
      int nn=t/144, f=t%144;
      if(nn<nvalid) sX[nn*148+f]=xf[(size_t)(node0+nn)*144+f];
    }
  }
  if(!df32){ for(int t=tid;t<768;t+=512) sWd[t]=bfu((unsigned int)wd[t]); }
  else     { const float* wdf=(const float*)wd; for(int t=tid;t<768;t+=512) sWd[t]=wdf[t]; }
  __syncthreads();

  const float scl[3]={0.03608439182435161f,0.05412658773652741f,0.06987712429686843f};

  #define PATH_STEP(P_,D1_,D2_,D3_) { \
    fusedAB<D1_,D2_,D3_>(sX,c3j+g_coff[P_],scl[(D3_-1)/2],sAu,wave,lane,nvalid); \
    __syncthreads(); \
    stage2_acc<(D3_-1)/2>(sAu,wpre+(size_t)P_*6720,a0,a1,n16,quad,wave); \
    __syncthreads(); }

  { // group l3=0: paths 0,1,2
    f32x4 a0={0.f,0.f,0.f,0.f}, a1={0.f,0.f,0.f,0.f};
    PATH_STEP(0,1,1,1)
    PATH_STEP(1,3,3,1)
    PATH_STEP(2,5,5,1)
    stage2_out<0>(a0,a1,sO,n16,quad,wave);
  }
  { // group l3=1: paths 3,4,5,6
    f32x4 a0={0.f,0.f,0.f,0.f}, a1={0.f,0.f,0.f,0.f};
    PATH_STEP(3,1,3,3)
    PATH_STEP(4,3,1,3)
    PATH_STEP(5,3,5,3)
    PATH_STEP(6,5,3,3)
    stage2_out<1>(a0,a1,sO,n16,quad,wave);
  }
  { // group l3=2: paths 7,8,9,10
    f32x4 a0={0.f,0.f,0.f,0.f}, a1={0.f,0.f,0.f,0.f};
    PATH_STEP(7,1,5,5)
    PATH_STEP(8,3,3,5)
    PATH_STEP(9,5,1,5)
    PATH_STEP(10,5,5,5)
    stage2_out<2>(a0,a1,sO,n16,quad,wave);
  }
  #undef PATH_STEP
  __syncthreads();

  // ---- epilogue: dot via C(l,l,0)=c_l*I; attention; elu; store ----
  {
    int node=wave;
    if(node<nvalid){
      const float c0=c3j[0], c1=c3j[1], c2=c3j[10];
      const float* qv=sO+node*440;
      const float* kv=qv+144;
      const int v=lane&15, ug=lane>>4;
      float k0=kv[v];
      float k1[3],k2[5];
      #pragma unroll
      for(int j=0;j<3;++j) k1[j]=kv[16+v*3+j];
      #pragma unroll
      for(int m=0;m<5;++m) k2[m]=kv[64+v*5+m];
      float part=0.f;
      #pragma unroll
      for(int t=0;t<4;++t){
        int u=ug+4*t;
        float d0=qv[u]*k0;
        float d1=0.f;
        #pragma unroll
        for(int j=0;j<3;++j) d1+=qv[16+u*3+j]*k1[j];
        float d2=0.f;
        #pragma unroll
        for(int m=0;m<5;++m) d2+=qv[64+u*5+m]*k2[m];
        part+=sWd[u*16+v]*(c0*d0)+sWd[256+u*16+v]*(c1*d1)+sWd[512+u*16+v]*(c2*d2);
      }
      #pragma unroll
      for(int off=1;off<64;off<<=1) part+=__shfl_xor(part,off,64);
      float dd=part*0.03608439182435161f;   // * sqrt(1/768)
      float ex=dd*(1.0f/12.0f);             // / sqrt(144)
      ex=fminf(fmaxf(ex,-80.f),80.f);
      float e=expf(ex);
      float attn=e/(e+1e-10f);
      const float* vv=sO+node*440+288;
      if(!xf32){
        unsigned short* ob=outp+(size_t)(node0+node)*144;
        for(int f=lane;f<144;f+=64){
          float val=attn*vv[f];
          float r=(val>0.f)?val:expm1f(val);
          ob[f]=(unsigned short)rne16(r);
        }
      }else{
        float* ob=(float*)outp+(size_t)(node0+node)*144;
        for(int f=lane;f<144;f+=64){
          float val=attn*vv[f];
          ob[f]=(val>0.f)?val:expm1f(val);
        }
      }
    }
  }
}

extern "C" void kernel_launch(void* const* d_in, const int* in_sizes, int n_in,
                              void* d_out, int out_size, void* d_ws, size_t ws_size,
                              hipStream_t stream){
  (void)n_in; (void)out_size; (void)ws_size;
  const unsigned short* x =(const unsigned short*)d_in[0];
  const unsigned short* wq=(const unsigned short*)d_in[4];
  const unsigned short* wk=(const unsigned short*)d_in[5];
  const unsigned short* wv=(const unsigned short*)d_in[6];
  const unsigned short* wd=(const unsigned short*)d_in[7];
  float* c3j=(float*)d_ws;                       // [0..362] w3j, [363..367] dtype flags
  unsigned int* wpre=(unsigned int*)((float*)d_ws+512);  // 11*3*2240 dwords fp16-pair weights
  int N=in_sizes[0]/144;
  w3j_init<<<dim3(NP),dim3(128),0,stream>>>(c3j);
  dtype_probe5<<<dim3(5),dim3(256),0,stream>>>(x,wq,wk,wv,wd,
      in_sizes[0],in_sizes[4],in_sizes[5],in_sizes[6],in_sizes[7],c3j+363);
  w_prep<<<dim3(NP,3),dim3(256),0,stream>>>(wq,wk,wv,c3j+364,wpre);
  int nb=(N+NN-1)/NN;
  tfn_main<<<dim3(nb),dim3(512),0,stream>>>(x,wpre,wd,c3j,(unsigned short*)d_out,N);
}

// Round 7
// 385.199 us; speedup vs baseline: 12.0140x; 1.0206x over previous
//
#include <hip/hip_runtime.h>
#include <math.h>

#define NP 11
#define NN 8    // nodes per block (512 threads, 8 waves)

__device__ __constant__ int g_l1[NP]   = {0,1,2,0,1,1,2,0,1,2,2};
__device__ __constant__ int g_l2[NP]   = {0,1,2,1,0,2,1,2,1,0,2};
__device__ __constant__ int g_l3[NP]   = {0,0,0,1,1,1,1,2,2,2,2};
__device__ __constant__ int g_coff[NP] = {0,1,10,35,44,53,98,143,168,213,238};

typedef _Float16 half8 __attribute__((ext_vector_type(8)));
typedef _Float16 h2 __attribute__((ext_vector_type(2)));
typedef float f32x4 __attribute__((ext_vector_type(4)));

// ---------------- Wigner-3j precompute (exact replica of reference, fp64) ----------------
__device__ double dfact(int n){ double r=1.0; for(int i=2;i<=n;++i) r*=(double)i; return r; }

__device__ double su2_cg(int j1,int m1,int j2,int m2,int j3,int m3){
  if(m1+m2!=m3) return 0.0;
  int vmin=-j1+j2+m3; if(-j1+m1>vmin) vmin=-j1+m1; if(vmin<0) vmin=0;
  int vmax=j2+j3+m1; int t=j3-j1+j2; if(t<vmax) vmax=t; t=j3+m3; if(t<vmax) vmax=t;
  double C = sqrt((double)(2*j3+1)*dfact(j3+j1-j2)*dfact(j3-j1+j2)*dfact(j1+j2-j3)
      *dfact(j3+m3)*dfact(j3-m3)
      /(dfact(j1+j2+j3+1)*dfact(j1-m1)*dfact(j1+m1)*dfact(j2-m2)*dfact(j2+m2)));
  double S=0.0;
  for(int v=vmin;v<=vmax;++v){
    double sg = ((v+j2+m2)&1)? -1.0:1.0;
    S += sg*dfact(j2+j3+m1-v)*dfact(j1-m1+v)
        /(dfact(v)*dfact(j3-j1+j2-v)*dfact(j3+m3-v)*dfact(v+j1-j2-m3));
  }
  return C*S;
}

__device__ void qelem(int l,int r,int c,double &re,double &im){
  int m=r-l; double a=0.0,b=0.0; const double s=0.70710678118654752440;
  if(m<0){ if(c==l-m) a=s; else if(c==l+m) b=-s; }
  else if(m==0){ if(c==l) a=1.0; }
  else { double sg=(m&1)?-1.0:1.0; if(c==l+m) a=sg*s; else if(c==l-m) b=sg*s; }
  if(l==1){ double tt=a; a=b; b=-tt; }
  else if(l==2){ a=-a; b=-b; }
  re=a; im=b;
}

__global__ void w3j_init(float* __restrict__ ws){
  int p=blockIdx.x;
  int l1=g_l1[p], l2=g_l2[p], l3=g_l3[p];
  int d1=2*l1+1, d2=2*l2+1, d3=2*l3+1;
  int tot=d1*d2*d3;
  __shared__ double cg[125];
  __shared__ double outv[125];
  __shared__ double nrm;
  for(int t=threadIdx.x;t<tot;t+=blockDim.x){
    int i=t/(d2*d3), k=(t/d3)%d2, n=t%d3;
    cg[t]=su2_cg(l1,i-l1,l2,k-l2,l3,n-l3);
  }
  __syncthreads();
  for(int t=threadIdx.x;t<tot;t+=blockDim.x){
    int a=t/(d2*d3), b=(t/d3)%d2, c=t%d3;
    double sre=0.0;
    for(int i=0;i<d1;++i){ double q1r,q1i; qelem(l1,i,a,q1r,q1i);
      for(int k=0;k<d2;++k){ double q2r,q2i; qelem(l2,k,b,q2r,q2i);
        double pr=q1r*q2r-q1i*q2i, pi=q1r*q2i+q1i*q2r;
        for(int n=0;n<d3;++n){ double q3r,q3i; qelem(l3,n,c,q3r,q3i);
          sre += (pr*q3r + pi*q3i) * cg[(i*d2+k)*d3+n];
        }
      }
    }
    outv[t]=sre;
  }
  __syncthreads();
  if(threadIdx.x==0){
    double s=0.0; for(int t=0;t<tot;++t) s+=outv[t]*outv[t];
    nrm=sqrt(s);
  }
  __syncthreads();
  for(int t=threadIdx.x;t<tot;t+=blockDim.x)
    ws[g_coff[p]+t]=(float)(outv[t]/nrm);
}

// ---------------- dtype probes (one launch, 5 blocks) ----------------
__global__ void dtype_probe5(const unsigned short* p0,const unsigned short* p1,
                             const unsigned short* p2,const unsigned short* p3,
                             const unsigned short* p4,
                             int n0,int n1,int n2,int n3,int n4,
                             float* __restrict__ flags){
  __shared__ int cnt;
  const unsigned short* ps[5]={p0,p1,p2,p3,p4};
  int ns[5]={n0,n1,n2,n3,n4};
  int b=blockIdx.x;
  const unsigned short* p=ps[b]; int nelem=ns[b];
  if(threadIdx.x==0) cnt=0;
  __syncthreads();
  int M = nelem < 4096 ? nelem : 4096;
  int c=0;
  for(int t=threadIdx.x;t<M;t+=blockDim.x){
    unsigned e=((unsigned)p[t]>>7)&0xFFu;
    if(e!=0u && (e<0x70u || e>0x8Eu)) ++c;
  }
  atomicAdd(&cnt,c);
  __syncthreads();
  if(threadIdx.x==0) flags[b] = (cnt*8 > M) ? 1.0f : 0.0f;
}

// ---------------- helpers ----------------
__device__ __forceinline__ float bfu(unsigned int v){ return __uint_as_float(v<<16); }
__device__ __forceinline__ unsigned int rne16(float f){
  unsigned int ui=__float_as_uint(f);
  return (ui+0x7fffu+((ui>>16)&1u))>>16;
}
__device__ __forceinline__ unsigned short h16(float f){
  _Float16 h=(_Float16)f;
  return __builtin_bit_cast(unsigned short,h);
}

// ---------------- packed (scale*C, scale*C) fp16 table ----------------
__global__ void c_pack(const float* __restrict__ c3j, unsigned int* __restrict__ cgh){
  int p=blockIdx.x;
  int d1=2*g_l1[p]+1, d2=2*g_l2[p]+1, d3=2*g_l3[p]+1;
  const float scl_[3]={0.03608439182435161f,0.05412658773652741f,0.06987712429686843f};
  float s=scl_[g_l3[p]];
  int tot=d1*d2*d3;
  for(int t=threadIdx.x;t<tot;t+=64){
    unsigned int h=(unsigned int)h16(c3j[g_coff[p]+t]*s);
    cgh[g_coff[p]+t]=h|(h<<16);
  }
}

// ---------------- weight pre-transpose: col c = vp*16+u; dword halves = (v=2vp, v=2vp+1) ----------------
// wpre[(p*3+tp)*2240 + w*140 + c] = pack_fp16(W[u*16+2vp][w], W[u*16+2vp+1][w]),  u=c&15, vp=c>>4
__global__ void w_prep(const unsigned short* __restrict__ wq,
                       const unsigned short* __restrict__ wk,
                       const unsigned short* __restrict__ wv,
                       const float* __restrict__ flags,   // {wq,wk,wv}
                       unsigned int* __restrict__ wpre){
  int p=blockIdx.x, tp=blockIdx.y;
  const unsigned short* ww=(tp==0)?wq:((tp==1)?wk:wv);
  int f32=flags[tp]!=0.0f;
  unsigned int* dst=wpre+(size_t)(p*3+tp)*2240;
  for(int t=threadIdx.x;t<2048;t+=256){
    int w=t>>7, c=t&127, u=c&15, vp=c>>4;
    int i0=(u*16+2*vp)*16+w, i1=i0+16;
    float f0,f1;
    if(f32){
      const float* wf=(const float*)ww+(size_t)p*4096;
      f0=wf[i0]; f1=wf[i1];
    }else{
      const unsigned short* wsp=ww+(size_t)p*4096;
      f0=bfu(wsp[i0]); f1=bfu(wsp[i1]);
    }
    dst[w*140+c]=(unsigned int)h16(f0)|((unsigned int)h16(f1)<<16);
  }
}

// ---------------- fused stage 1, all-packed fp16 ----------------
// A[row=k*8+nn][col c=vp*16+u] halves(v=2vp,2vp+1) = sum_i x1[u,i]*( sum_j sC[ijk]*x2[v,j] )
template<int D1,int D2,int D3>
__device__ __forceinline__ void fusedAB(const unsigned int* __restrict__ sXp,
                                        const unsigned int* __restrict__ sXd,
                                        const unsigned int* __restrict__ cgp,
                                        unsigned int* __restrict__ sAu,
                                        int wave, int lane, int nvalid){
  constexpr int O1=(D1==1)?0:((D1==3)?16:64);
  constexpr int O2P=(D2==1)?0:((D2==3)?8:32);
  const int nn=lane>>3, vp=lane&7;
  if(nn>=nvalid) return;
  h2 x2p[D2];
  #pragma unroll
  for(int j=0;j<D2;++j) x2p[j]=__builtin_bit_cast(h2,sXp[nn*76+O2P+vp*D2+j]);
  const int u0=wave*2;
  h2 x1a[D1],x1b[D1];
  #pragma unroll
  for(int i=0;i<D1;++i){
    x1a[i]=__builtin_bit_cast(h2,sXd[nn*148+O1+u0*D1+i]);
    x1b[i]=__builtin_bit_cast(h2,sXd[nn*148+O1+(u0+1)*D1+i]);
  }
  h2 acc0[D3],acc1[D3];
  #pragma unroll
  for(int k=0;k<D3;++k){ acc0[k]=(h2){(_Float16)0.f,(_Float16)0.f}; acc1[k]=acc0[k]; }
  #pragma unroll
  for(int i=0;i<D1;++i){
    #pragma unroll
    for(int k=0;k<D3;++k){
      h2 ar=(h2){(_Float16)0.f,(_Float16)0.f};
      #pragma unroll
      for(int j=0;j<D2;++j)
        ar+=__builtin_bit_cast(h2,cgp[(i*D2+j)*D3+k])*x2p[j];
      acc0[k]+=x1a[i]*ar;
      acc1[k]+=x1b[i]*ar;
    }
  }
  #pragma unroll
  for(int k=0;k<D3;++k){
    uint2 st;
    st.x=__builtin_bit_cast(unsigned int,acc0[k]);
    st.y=__builtin_bit_cast(unsigned int,acc1[k]);
    *(uint2*)(sAu+(k*8+nn)*140+vp*16+u0)=st;
  }
}

// ---------------- stage 2: MFMA, A from LDS (stride 140), B from global/L2 ----------------
template<int L3>
__device__ __forceinline__ void stage2_acc(const unsigned int* __restrict__ sAu,
                                           const unsigned int* __restrict__ wp_path,
                                           f32x4& a0, f32x4& a1,
                                           int n16, int quad, int wave){
  constexpr int P=(L3+1)*3;
  if(wave<P){
    int tp=wave%3, Mt=wave/3;
    const unsigned int* ap=sAu+(Mt*16+n16)*140+quad*4;
    const uint4* bp=(const uint4*)(wp_path+tp*2240+n16*140+quad*4);
    uint4 b[8];
    #pragma unroll
    for(int ks=0;ks<8;++ks) b[ks]=bp[ks*4];
    f32x4 a=a0;
    #pragma unroll
    for(int ks=0;ks<8;++ks)
      a=__builtin_amdgcn_mfma_f32_16x16x32_f16(
          *reinterpret_cast<const half8*>(ap+ks*16),
          __builtin_bit_cast(half8,b[ks]),a,0,0,0);
    a0=a;
  }
  if(L3==2 && wave==0){           // pid 8: tp=2, Mt=2
    const unsigned int* ap=sAu+(2*16+n16)*140+quad*4;
    const uint4* bp=(const uint4*)(wp_path+2*2240+n16*140+quad*4);
    uint4 b[8];
    #pragma unroll
    for(int ks=0;ks<8;++ks) b[ks]=bp[ks*4];
    f32x4 a=a1;
    #pragma unroll
    for(int ks=0;ks<8;++ks)
      a=__builtin_amdgcn_mfma_f32_16x16x32_f16(
          *reinterpret_cast<const half8*>(ap+ks*16),
          __builtin_bit_cast(half8,b[ks]),a,0,0,0);
    a1=a;
  }
}

template<int L3>
__device__ __forceinline__ void stage2_out(const f32x4& a0, const f32x4& a1,
                                           float* __restrict__ sO,
                                           int n16, int quad, int wave){
  constexpr int D3=2*L3+1;
  constexpr int OO=(L3==0)?0:((L3==1)?16:64);
  constexpr int P=(L3+1)*3;
  if(wave<P){
    int tp=wave%3, Mt=wave/3;
    #pragma unroll
    for(int reg=0;reg<4;++reg){
      int row=Mt*16+quad*4+reg;
      int k=row>>3, node=row&7;
      if(k<D3) sO[node*440+tp*144+OO+n16*D3+k]=a0[reg];
    }
  }
  if(L3==2 && wave==0){
    #pragma unroll
    for(int reg=0;reg<4;++reg){
      int row=32+quad*4+reg;
      int k=row>>3, node=row&7;
      if(k<D3) sO[node*440+2*144+OO+n16*D3+k]=a1[reg];
    }
  }
}

__global__ __launch_bounds__(512,6) void tfn_main(
    const unsigned short* __restrict__ xin,
    const unsigned int* __restrict__ wpre,
    const unsigned int* __restrict__ cgh,
    const unsigned short* __restrict__ wd,
    const float* __restrict__ c3j,
    unsigned short* __restrict__ outp, int N)
{
  __shared__ __align__(16) unsigned int sAu[48*140];  // fp16 A, row stride 140 dwords
  __shared__ float sO[NN*440];                        // also staging scratch for fp32 x
  __shared__ __align__(8) unsigned int sXp[NN*76];    // (v,v+1)-pair packs per (vp,j)
  __shared__ __align__(8) unsigned int sXd[NN*148];   // (x,x) dup packs per feature
  __shared__ float sWd[768];

  const int tid=threadIdx.x;
  const int wave=tid>>6, lane=tid&63;
  const int n16=lane&15, quad=lane>>4;
  const int node0=blockIdx.x*NN;
  const int nvalid=(N-node0)<NN?(N-node0):NN;

  const int xf32 = c3j[363]!=0.0f;
  const int df32 = c3j[367]!=0.0f;

  // ---- stage x into fp32 scratch (sO reused; consumed before first stage2_out) ----
  float* scratch=sO;
  if(!xf32){
    for(int t=tid;t<NN*36;t+=512){
      int nn=t/36, w4=t%36;
      if(nn<nvalid){
        uint2 u=((const uint2*)(xin+(size_t)(node0+nn)*144))[w4];
        float* dst=&scratch[nn*144+w4*4];
        dst[0]=bfu(u.x&0xffffu); dst[1]=bfu(u.x>>16);
        dst[2]=bfu(u.y&0xffffu); dst[3]=bfu(u.y>>16);
      }
    }
  }else{
    const float* xf=(const float*)xin;
    for(int t=tid;t<NN*144;t+=512){
      int nn=t/144, f=t%144;
      if(nn<nvalid) scratch[nn*144+f]=xf[(size_t)(node0+nn)*144+f];
    }
  }
  if(!df32){ for(int t=tid;t<768;t+=512) sWd[t]=bfu((unsigned int)wd[t]); }
  else     { const float* wdf=(const float*)wd; for(int t=tid;t<768;t+=512) sWd[t]=wdf[t]; }
  __syncthreads();

  // ---- build packed images ----
  for(int t=tid;t<NN*144;t+=512){
    int nn=t/144, f=t-nn*144;
    unsigned int h=(unsigned int)h16(scratch[t]);
    sXd[nn*148+f]=h|(h<<16);
  }
  for(int t=tid;t<NN*72;t+=512){
    int nn=t/72, g=t-nn*72;
    int fa,fb;
    if(g<8){ fa=2*g; fb=fa+1; }
    else if(g<32){ int gg=g-8; int vp=gg/3, j=gg-3*vp; fa=16+(2*vp)*3+j; fb=fa+3; }
    else { int gg=g-32; int vp=gg/5, j=gg-5*vp; fa=64+(2*vp)*5+j; fb=fa+5; }
    sXp[nn*76+g]=(unsigned int)h16(scratch[nn*144+fa])|((unsigned int)h16(scratch[nn*144+fb])<<16);
  }
  __syncthreads();

  #define PATH_STEP(P_,D1_,D2_,D3_) { \
    fusedAB<D1_,D2_,D3_>(sXp,sXd,cgh+g_coff[P_],sAu,wave,lane,nvalid); \
    __syncthreads(); \
    stage2_acc<(D3_-1)/2>(sAu,wpre+(size_t)P_*6720,a0,a1,n16,quad,wave); \
    __syncthreads(); }

  { // group l3=0: paths 0,1,2
    f32x4 a0={0.f,0.f,0.f,0.f}, a1={0.f,0.f,0.f,0.f};
    PATH_STEP(0,1,1,1)
    PATH_STEP(1,3,3,1)
    PATH_STEP(2,5,5,1)
    stage2_out<0>(a0,a1,sO,n16,quad,wave);
  }
  { // group l3=1: paths 3,4,5,6
    f32x4 a0={0.f,0.f,0.f,0.f}, a1={0.f,0.f,0.f,0.f};
    PATH_STEP(3,1,3,3)
    PATH_STEP(4,3,1,3)
    PATH_STEP(5,3,5,3)
    PATH_STEP(6,5,3,3)
    stage2_out<1>(a0,a1,sO,n16,quad,wave);
  }
  { // group l3=2: paths 7,8,9,10
    f32x4 a0={0.f,0.f,0.f,0.f}, a1={0.f,0.f,0.f,0.f};
    PATH_STEP(7,1,5,5)
    PATH_STEP(8,3,3,5)
    PATH_STEP(9,5,1,5)
    PATH_STEP(10,5,5,5)
    stage2_out<2>(a0,a1,sO,n16,quad,wave);
  }
  #undef PATH_STEP
  __syncthreads();

  // ---- epilogue: dot via C(l,l,0)=c_l*I; attention; elu; store ----
  {
    int node=wave;
    if(node<nvalid){
      const float c0=c3j[0], c1=c3j[1], c2=c3j[10];
      const float* qv=sO+node*440;
      const float* kv=qv+144;
      const int v=lane&15, ug=lane>>4;
      float k0=kv[v];
      float k1[3],k2[5];
      #pragma unroll
      for(int j=0;j<3;++j) k1[j]=kv[16+v*3+j];
      #pragma unroll
      for(int m=0;m<5;++m) k2[m]=kv[64+v*5+m];
      float part=0.f;
      #pragma unroll
      for(int t=0;t<4;++t){
        int u=ug+4*t;
        float d0=qv[u]*k0;
        float d1=0.f;
        #pragma unroll
        for(int j=0;j<3;++j) d1+=qv[16+u*3+j]*k1[j];
        float d2=0.f;
        #pragma unroll
        for(int m=0;m<5;++m) d2+=qv[64+u*5+m]*k2[m];
        part+=sWd[u*16+v]*(c0*d0)+sWd[256+u*16+v]*(c1*d1)+sWd[512+u*16+v]*(c2*d2);
      }
      #pragma unroll
      for(int off=1;off<64;off<<=1) part+=__shfl_xor(part,off,64);
      float dd=part*0.03608439182435161f;   // * sqrt(1/768)
      float ex=dd*(1.0f/12.0f);             // / sqrt(144)
      ex=fminf(fmaxf(ex,-80.f),80.f);
      float e=expf(ex);
      float attn=e/(e+1e-10f);
      const float* vv=sO+node*440+288;
      if(!xf32){
        unsigned short* ob=outp+(size_t)(node0+node)*144;
        for(int f=lane;f<144;f+=64){
          float val=attn*vv[f];
          float r=(val>0.f)?val:expm1f(val);
          ob[f]=(unsigned short)rne16(r);
        }
      }else{
        float* ob=(float*)outp+(size_t)(node0+node)*144;
        for(int f=lane;f<144;f+=64){
          float val=attn*vv[f];
          ob[f]=(val>0.f)?val:expm1f(val);
        }
      }
    }
  }
}

extern "C" void kernel_launch(void* const* d_in, const int* in_sizes, int n_in,
                              void* d_out, int out_size, void* d_ws, size_t ws_size,
                              hipStream_t stream){
  (void)n_in; (void)out_size; (void)ws_size;
  const unsigned short* x =(const unsigned short*)d_in[0];
  const unsigned short* wq=(const unsigned short*)d_in[4];
  const unsigned short* wk=(const unsigned short*)d_in[5];
  const unsigned short* wv=(const unsigned short*)d_in[6];
  const unsigned short* wd=(const unsigned short*)d_in[7];
  float* c3j=(float*)d_ws;                                 // [0..362] w3j, [363..367] flags
  unsigned int* cgh=(unsigned int*)d_ws+1024;              // packed scale*C fp16 pairs (363)
  unsigned int* wpre=(unsigned int*)d_ws+2048;             // 11*3*2240 packed fp16 W^T
  int N=in_sizes[0]/144;
  w3j_init<<<dim3(NP),dim3(128),0,stream>>>(c3j);
  dtype_probe5<<<dim3(5),dim3(256),0,stream>>>(x,wq,wk,wv,wd,
      in_sizes[0],in_sizes[4],in_sizes[5],in_sizes[6],in_sizes[7],c3j+363);
  c_pack<<<dim3(NP),dim3(64),0,stream>>>(c3j,cgh);
  w_prep<<<dim3(NP,3),dim3(256),0,stream>>>(wq,wk,wv,c3j+364,wpre);
  int nb=(N+NN-1)/NN;
  tfn_main<<<dim3(nb),dim3(512),0,stream>>>(x,wpre,cgh,wd,c3j,(unsigned short*)d_out,N);
}

// Round 8
// 355.439 us; speedup vs baseline: 13.0199x; 1.0837x over previous
//
#include <hip/hip_runtime.h>
#include <math.h>

#define NP 11
#define NN 8    // nodes per block (512 threads, 8 waves)

__device__ __constant__ int g_l1[NP]   = {0,1,2,0,1,1,2,0,1,2,2};
__device__ __constant__ int g_l2[NP]   = {0,1,2,1,0,2,1,2,1,0,2};
__device__ __constant__ int g_l3[NP]   = {0,0,0,1,1,1,1,2,2,2,2};
__device__ __constant__ int g_coff[NP] = {0,1,10,35,44,53,98,143,168,213,238};

typedef _Float16 half8 __attribute__((ext_vector_type(8)));
typedef _Float16 h2 __attribute__((ext_vector_type(2)));
typedef float f32x4 __attribute__((ext_vector_type(4)));

// ---------------- helpers ----------------
__device__ __forceinline__ float bfu(unsigned int v){ return __uint_as_float(v<<16); }
__device__ __forceinline__ unsigned int rne16(float f){
  unsigned int ui=__float_as_uint(f);
  return (ui+0x7fffu+((ui>>16)&1u))>>16;
}
__device__ __forceinline__ unsigned short h16(float f){
  _Float16 h=(_Float16)f;
  return __builtin_bit_cast(unsigned short,h);
}

// ---------------- Wigner-3j pieces (exact replica of reference, fp64) ----------------
__device__ double dfact(int n){ double r=1.0; for(int i=2;i<=n;++i) r*=(double)i; return r; }

__device__ double su2_cg(int j1,int m1,int j2,int m2,int j3,int m3){
  if(m1+m2!=m3) return 0.0;
  int vmin=-j1+j2+m3; if(-j1+m1>vmin) vmin=-j1+m1; if(vmin<0) vmin=0;
  int vmax=j2+j3+m1; int t=j3-j1+j2; if(t<vmax) vmax=t; t=j3+m3; if(t<vmax) vmax=t;
  double C = sqrt((double)(2*j3+1)*dfact(j3+j1-j2)*dfact(j3-j1+j2)*dfact(j1+j2-j3)
      *dfact(j3+m3)*dfact(j3-m3)
      /(dfact(j1+j2+j3+1)*dfact(j1-m1)*dfact(j1+m1)*dfact(j2-m2)*dfact(j2+m2)));
  double S=0.0;
  for(int v=vmin;v<=vmax;++v){
    double sg = ((v+j2+m2)&1)? -1.0:1.0;
    S += sg*dfact(j2+j3+m1-v)*dfact(j1-m1+v)
        /(dfact(v)*dfact(j3-j1+j2-v)*dfact(j3+m3-v)*dfact(v+j1-j2-m3));
  }
  return C*S;
}

__device__ void qelem(int l,int r,int c,double &re,double &im){
  int m=r-l; double a=0.0,b=0.0; const double s=0.70710678118654752440;
  if(m<0){ if(c==l-m) a=s; else if(c==l+m) b=-s; }
  else if(m==0){ if(c==l) a=1.0; }
  else { double sg=(m&1)?-1.0:1.0; if(c==l+m) a=sg*s; else if(c==l-m) b=sg*s; }
  if(l==1){ double tt=a; a=b; b=-tt; }
  else if(l==2){ a=-a; b=-b; }
  re=a; im=b;
}

// in-block probe: 1 if buffer looks like fp32-reinterpreted shorts
__device__ int probe_f32(const unsigned short* __restrict__ p, int nelem, int* scnt){
  if(threadIdx.x==0) *scnt=0;
  __syncthreads();
  int M = nelem < 4096 ? nelem : 4096;
  int c=0;
  for(int t=threadIdx.x;t<M;t+=blockDim.x){
    unsigned e=((unsigned)p[t]>>7)&0xFFu;
    if(e!=0u && (e<0x70u || e>0x8Eu)) ++c;
  }
  atomicAdd(scnt,c);
  __syncthreads();
  return (*scnt*8 > M) ? 1 : 0;
}

// ---------------- ONE prep kernel: w3j + c3j/cgh tables + dtype flags + weight transpose ----------------
// grid (NP, 3), 256 threads.
// wpre[(p*3+tp)*2240 + w*140 + c] = pack_fp16(W[2c][w], W[2c+1][w])  (uv=2c -> u=c>>3, v=2(c&7))
__global__ void prep(const unsigned short* __restrict__ x,
                     const unsigned short* __restrict__ wq,
                     const unsigned short* __restrict__ wk,
                     const unsigned short* __restrict__ wv,
                     const unsigned short* __restrict__ wd,
                     int nx,int nw,int nd,
                     float* __restrict__ c3j, unsigned int* __restrict__ cgh,
                     unsigned int* __restrict__ wpre){
  const int p=blockIdx.x, tp=blockIdx.y;
  __shared__ double cg[125];
  __shared__ double outv[125];
  __shared__ double nrm;
  __shared__ int scnt;

  const unsigned short* ww=(tp==0)?wq:((tp==1)?wk:wv);
  const int f32 = probe_f32(ww,nw,&scnt);

  // weight transpose (fp16 pair pack), col c = u*8+vp
  {
    unsigned int* dst=wpre+(size_t)(p*3+tp)*2240;
    for(int t=threadIdx.x;t<2048;t+=256){
      int w=t>>7, c=t&127;
      int i0=c*32+w, i1=i0+16;
      float f0,f1;
      if(f32){
        const float* wf=(const float*)ww+(size_t)p*4096;
        f0=wf[i0]; f1=wf[i1];
      }else{
        const unsigned short* wsp=ww+(size_t)p*4096;
        f0=bfu(wsp[i0]); f1=bfu(wsp[i1]);
      }
      dst[w*140+c]=(unsigned int)h16(f0)|((unsigned int)h16(f1)<<16);
    }
  }

  if(tp==0){
    // w3j for path p (exact reference pipeline, fp64)
    int l1=g_l1[p], l2=g_l2[p], l3=g_l3[p];
    int d1=2*l1+1, d2=2*l2+1, d3=2*l3+1;
    int tot=d1*d2*d3;
    for(int t=threadIdx.x;t<tot;t+=256){
      int i=t/(d2*d3), k=(t/d3)%d2, n=t%d3;
      cg[t]=su2_cg(l1,i-l1,l2,k-l2,l3,n-l3);
    }
    __syncthreads();
    for(int t=threadIdx.x;t<tot;t+=256){
      int a=t/(d2*d3), b=(t/d3)%d2, c=t%d3;
      double sre=0.0;
      for(int i=0;i<d1;++i){ double q1r,q1i; qelem(l1,i,a,q1r,q1i);
        for(int k=0;k<d2;++k){ double q2r,q2i; qelem(l2,k,b,q2r,q2i);
          double pr=q1r*q2r-q1i*q2i, pi=q1r*q2i+q1i*q2r;
          for(int n=0;n<d3;++n){ double q3r,q3i; qelem(l3,n,c,q3r,q3i);
            sre += (pr*q3r + pi*q3i) * cg[(i*d2+k)*d3+n];
          }
        }
      }
      outv[t]=sre;
    }
    __syncthreads();
    if(threadIdx.x==0){
      double s=0.0; for(int t=0;t<tot;++t) s+=outv[t]*outv[t];
      nrm=sqrt(s);
    }
    __syncthreads();
    const float scl_[3]={0.03608439182435161f,0.05412658773652741f,0.06987712429686843f};
    float s=scl_[l3];
    for(int t=threadIdx.x;t<tot;t+=256){
      float val=(float)(outv[t]/nrm);
      c3j[g_coff[p]+t]=val;
      unsigned int h=(unsigned int)h16(val*s);
      cgh[g_coff[p]+t]=h|(h<<16);
    }
  }

  if(p==0 && tp==0){
    int xf=probe_f32(x,nx,&scnt);
    if(threadIdx.x==0) c3j[363]=(float)xf;
    int df=probe_f32(wd,nd,&scnt);
    if(threadIdx.x==0) c3j[367]=(float)df;
  }
}

// ---------------- fused stage 1, all-packed fp16 ----------------
// A[row=k*8+nn][col c=u*8+vp] halves(v=2vp,2vp+1) = sum_i x1[u,i]*( sum_j sC[ijk]*x2[v,j] )
template<int D1,int D2,int D3>
__device__ __forceinline__ void fusedAB(const unsigned int* __restrict__ sXp,
                                        const unsigned int* __restrict__ sXd,
                                        const unsigned int* __restrict__ cgp,
                                        unsigned int* __restrict__ sAu,
                                        int wave, int lane, int nvalid){
  constexpr int O1=(D1==1)?0:((D1==3)?16:64);
  constexpr int O2P=(D2==1)?0:((D2==3)?8:32);
  const int nn=lane>>3, vp=lane&7;
  if(nn>=nvalid) return;
  h2 x2p[D2];
  #pragma unroll
  for(int j=0;j<D2;++j) x2p[j]=__builtin_bit_cast(h2,sXp[nn*76+O2P+vp*D2+j]);
  const int u0=wave*2;
  h2 x1a[D1],x1b[D1];
  #pragma unroll
  for(int i=0;i<D1;++i){
    x1a[i]=__builtin_bit_cast(h2,sXd[nn*148+O1+u0*D1+i]);
    x1b[i]=__builtin_bit_cast(h2,sXd[nn*148+O1+(u0+1)*D1+i]);
  }
  h2 acc0[D3],acc1[D3];
  #pragma unroll
  for(int k=0;k<D3;++k){ acc0[k]=(h2){(_Float16)0.f,(_Float16)0.f}; acc1[k]=acc0[k]; }
  #pragma unroll
  for(int i=0;i<D1;++i){
    #pragma unroll
    for(int k=0;k<D3;++k){
      h2 ar=(h2){(_Float16)0.f,(_Float16)0.f};
      #pragma unroll
      for(int j=0;j<D2;++j)
        ar+=__builtin_bit_cast(h2,cgp[(i*D2+j)*D3+k])*x2p[j];
      acc0[k]+=x1a[i]*ar;
      acc1[k]+=x1b[i]*ar;
    }
  }
  #pragma unroll
  for(int k=0;k<D3;++k){
    sAu[(k*8+nn)*140+u0*8+vp]   =__builtin_bit_cast(unsigned int,acc0[k]);
    sAu[(k*8+nn)*140+u0*8+vp+8] =__builtin_bit_cast(unsigned int,acc1[k]);
  }
}

// ---------------- stage 2: MFMA, A from LDS, B prefetched in regs ----------------
template<int L3>
__device__ __forceinline__ void stage2_acc(const unsigned int* __restrict__ sAu,
                                           const unsigned int* __restrict__ wp_path,
                                           const uint4* __restrict__ bf,
                                           f32x4& a0, f32x4& a1,
                                           int n16, int quad, int wave){
  constexpr int P=(L3+1)*3;
  if(wave<P){
    int Mt=wave/3;
    const unsigned int* ap=sAu+(Mt*16+n16)*140+quad*4;
    f32x4 a=a0;
    #pragma unroll
    for(int ks=0;ks<8;++ks)
      a=__builtin_amdgcn_mfma_f32_16x16x32_f16(
          *reinterpret_cast<const half8*>(ap+ks*16),
          __builtin_bit_cast(half8,bf[ks]),a,0,0,0);
    a0=a;
  }
  if(L3==2 && wave==0){           // pid 8: tp=2, Mt=2 (inline B load, only 4 paths)
    const unsigned int* ap=sAu+(2*16+n16)*140+quad*4;
    const uint4* bp=(const uint4*)(wp_path+2*2240+n16*140+quad*4);
    uint4 b2[8];
    #pragma unroll
    for(int ks=0;ks<8;++ks) b2[ks]=bp[ks*4];
    f32x4 a=a1;
    #pragma unroll
    for(int ks=0;ks<8;++ks)
      a=__builtin_amdgcn_mfma_f32_16x16x32_f16(
          *reinterpret_cast<const half8*>(ap+ks*16),
          __builtin_bit_cast(half8,b2[ks]),a,0,0,0);
    a1=a;
  }
}

template<int L3>
__device__ __forceinline__ void stage2_out(const f32x4& a0, const f32x4& a1,
                                           float* __restrict__ sO,
                                           int n16, int quad, int wave){
  constexpr int D3=2*L3+1;
  constexpr int OO=(L3==0)?0:((L3==1)?16:64);
  constexpr int P=(L3+1)*3;
  if(wave<P){
    int tp=wave%3, Mt=wave/3;
    #pragma unroll
    for(int reg=0;reg<4;++reg){
      int row=Mt*16+quad*4+reg;
      int k=row>>3, node=row&7;
      if(k<D3) sO[node*440+tp*144+OO+n16*D3+k]=a0[reg];
    }
  }
  if(L3==2 && wave==0){
    #pragma unroll
    for(int reg=0;reg<4;++reg){
      int row=32+quad*4+reg;
      int k=row>>3, node=row&7;
      if(k<D3) sO[node*440+2*144+OO+n16*D3+k]=a1[reg];
    }
  }
}

__global__ __launch_bounds__(512,6) void tfn_main(
    const unsigned short* __restrict__ xin,
    const unsigned int* __restrict__ wpre,
    const unsigned int* __restrict__ cgh,
    const unsigned short* __restrict__ wd,
    const float* __restrict__ c3j,
    unsigned short* __restrict__ outp, int N)
{
  __shared__ __align__(16) unsigned int sAu[48*140];  // fp16 A, row stride 140 dwords
  __shared__ float sO[NN*440];                        // also staging scratch for fp32 x
  __shared__ __align__(8) unsigned int sXp[NN*76];    // (v,v+1)-pair packs per (vp,j)
  __shared__ __align__(8) unsigned int sXd[NN*148];   // (x,x) dup packs per feature
  __shared__ float sWd[768];

  const int tid=threadIdx.x;
  const int wave=tid>>6, lane=tid&63;
  const int n16=lane&15, quad=lane>>4;
  const int node0=blockIdx.x*NN;
  const int nvalid=(N-node0)<NN?(N-node0):NN;

  const int xf32 = c3j[363]!=0.0f;
  const int df32 = c3j[367]!=0.0f;

  // ---- stage x into fp32 scratch (sO reused; consumed before first stage2_out) ----
  float* scratch=sO;
  if(!xf32){
    for(int t=tid;t<NN*36;t+=512){
      int nn=t/36, w4=t%36;
      if(nn<nvalid){
        uint2 u=((const uint2*)(xin+(size_t)(node0+nn)*144))[w4];
        float* dst=&scratch[nn*144+w4*4];
        dst[0]=bfu(u.x&0xffffu); dst[1]=bfu(u.x>>16);
        dst[2]=bfu(u.y&0xffffu); dst[3]=bfu(u.y>>16);
      }
    }
  }else{
    const float* xf=(const float*)xin;
    for(int t=tid;t<NN*144;t+=512){
      int nn=t/144, f=t%144;
      if(nn<nvalid) scratch[nn*144+f]=xf[(size_t)(node0+nn)*144+f];
    }
  }
  if(!df32){ for(int t=tid;t<768;t+=512) sWd[t]=bfu((unsigned int)wd[t]); }
  else     { const float* wdf=(const float*)wd; for(int t=tid;t<768;t+=512) sWd[t]=wdf[t]; }
  __syncthreads();

  // ---- build packed images ----
  for(int t=tid;t<NN*144;t+=512){
    int nn=t/144, f=t-nn*144;
    unsigned int h=(unsigned int)h16(scratch[t]);
    sXd[nn*148+f]=h|(h<<16);
  }
  for(int t=tid;t<NN*72;t+=512){
    int nn=t/72, g=t-nn*72;
    int fa,fb;
    if(g<8){ fa=2*g; fb=fa+1; }
    else if(g<32){ int gg=g-8; int vp=gg/3, j=gg-3*vp; fa=16+(2*vp)*3+j; fb=fa+3; }
    else { int gg=g-32; int vp=gg/5, j=gg-5*vp; fa=64+(2*vp)*5+j; fb=fa+5; }
    sXp[nn*76+g]=(unsigned int)h16(scratch[nn*144+fa])|((unsigned int)h16(scratch[nn*144+fb])<<16);
  }
  __syncthreads();

  // one path step: prefetch B (regs), fusedAB, barrier, MFMA, barrier
  #define PATH_STEP(P_,D1_,D2_,D3_) { \
    const int PT=((D3_-1)/2+1)*3; \
    uint4 bf[8]; \
    if(wave<PT){ \
      const uint4* bp=(const uint4*)(wpre+(size_t)P_*6720+(wave%3)*2240+n16*140+quad*4); \
      bf[0]=bp[0];  bf[1]=bp[4];  bf[2]=bp[8];  bf[3]=bp[12]; \
      bf[4]=bp[16]; bf[5]=bp[20]; bf[6]=bp[24]; bf[7]=bp[28]; \
    } \
    fusedAB<D1_,D2_,D3_>(sXp,sXd,cgh+g_coff[P_],sAu,wave,lane,nvalid); \
    __syncthreads(); \
    stage2_acc<(D3_-1)/2>(sAu,wpre+(size_t)P_*6720,bf,a0,a1,n16,quad,wave); \
    __syncthreads(); }

  { // group l3=0: paths 0,1,2
    f32x4 a0={0.f,0.f,0.f,0.f}, a1={0.f,0.f,0.f,0.f};
    PATH_STEP(0,1,1,1)
    PATH_STEP(1,3,3,1)
    PATH_STEP(2,5,5,1)
    stage2_out<0>(a0,a1,sO,n16,quad,wave);
  }
  { // group l3=1: paths 3,4,5,6
    f32x4 a0={0.f,0.f,0.f,0.f}, a1={0.f,0.f,0.f,0.f};
    PATH_STEP(3,1,3,3)
    PATH_STEP(4,3,1,3)
    PATH_STEP(5,3,5,3)
    PATH_STEP(6,5,3,3)
    stage2_out<1>(a0,a1,sO,n16,quad,wave);
  }
  { // group l3=2: paths 7,8,9,10
    f32x4 a0={0.f,0.f,0.f,0.f}, a1={0.f,0.f,0.f,0.f};
    PATH_STEP(7,1,5,5)
    PATH_STEP(8,3,3,5)
    PATH_STEP(9,5,1,5)
    PATH_STEP(10,5,5,5)
    stage2_out<2>(a0,a1,sO,n16,quad,wave);
  }
  #undef PATH_STEP
  __syncthreads();

  // ---- epilogue: dot via C(l,l,0)=c_l*I; attention; elu; store ----
  {
    int node=wave;
    if(node<nvalid){
      const float c0=c3j[0], c1=c3j[1], c2=c3j[10];
      const float* qv=sO+node*440;
      const float* kv=qv+144;
      const int v=lane&15, ug=lane>>4;
      float k0=kv[v];
      float k1[3],k2[5];
      #pragma unroll
      for(int j=0;j<3;++j) k1[j]=kv[16+v*3+j];
      #pragma unroll
      for(int m=0;m<5;++m) k2[m]=kv[64+v*5+m];
      float part=0.f;
      #pragma unroll
      for(int t=0;t<4;++t){
        int u=ug+4*t;
        float d0=qv[u]*k0;
        float d1=0.f;
        #pragma unroll
        for(int j=0;j<3;++j) d1+=qv[16+u*3+j]*k1[j];
        float d2=0.f;
        #pragma unroll
        for(int m=0;m<5;++m) d2+=qv[64+u*5+m]*k2[m];
        part+=sWd[u*16+v]*(c0*d0)+sWd[256+u*16+v]*(c1*d1)+sWd[512+u*16+v]*(c2*d2);
      }
      #pragma unroll
      for(int off=1;off<64;off<<=1) part+=__shfl_xor(part,off,64);
      float dd=part*0.03608439182435161f;   // * sqrt(1/768)
      float ex=dd*(1.0f/12.0f);             // / sqrt(144)
      ex=fminf(fmaxf(ex,-80.f),80.f);
      float e=expf(ex);
      float attn=e/(e+1e-10f);
      const float* vv=sO+node*440+288;
      if(!xf32){
        unsigned short* ob=outp+(size_t)(node0+node)*144;
        for(int f=lane;f<144;f+=64){
          float val=attn*vv[f];
          float r=(val>0.f)?val:expm1f(val);
          ob[f]=(unsigned short)rne16(r);
        }
      }else{
        float* ob=(float*)outp+(size_t)(node0+node)*144;
        for(int f=lane;f<144;f+=64){
          float val=attn*vv[f];
          ob[f]=(val>0.f)?val:expm1f(val);
        }
      }
    }
  }
}

extern "C" void kernel_launch(void* const* d_in, const int* in_sizes, int n_in,
                              void* d_out, int out_size, void* d_ws, size_t ws_size,
                              hipStream_t stream){
  (void)n_in; (void)out_size; (void)ws_size;
  const unsigned short* x =(const unsigned short*)d_in[0];
  const unsigned short* wq=(const unsigned short*)d_in[4];
  const unsigned short* wk=(const unsigned short*)d_in[5];
  const unsigned short* wv=(const unsigned short*)d_in[6];
  const unsigned short* wd=(const unsigned short*)d_in[7];
  float* c3j=(float*)d_ws;                                 // [0..362] w3j, [363..367] flags
  unsigned int* cgh=(unsigned int*)d_ws+1024;              // packed scale*C fp16 pairs (363)
  unsigned int* wpre=(unsigned int*)d_ws+2048;             // 11*3*2240 packed fp16 W^T
  int N=in_sizes[0]/144;
  prep<<<dim3(NP,3),dim3(256),0,stream>>>(x,wq,wk,wv,wd,
      in_sizes[0],in_sizes[4],in_sizes[7],c3j,cgh,wpre);
  int nb=(N+NN-1)/NN;
  tfn_main<<<dim3(nb),dim3(512),0,stream>>>(x,wpre,cgh,wd,c3j,(unsigned short*)d_out,N);
}